// Round 2
// baseline (6716.739 us; speedup 1.0000x reference)
//
#include <hip/hip_runtime.h>
#include <cstddef>

#define Bg 128
#define Nn 100
#define Eg 800
#define TNODE 12800
#define TEDGE 102400
#define HD 256
#define NEMB 128
#define REMB 256

__device__ __forceinline__ float relu_(float x){ return x > 0.f ? x : 0.f; }
__device__ __forceinline__ float sigm_(float x){ return 1.f/(1.f + __expf(-x)); }

// ---------------- generic tiled f32 GEMM:  C[M,N] = epi(A[M,K] @ W[N,K]^T) ----------------
enum { A_PLAIN=0, A_ADD=1, A_RELUB=2, A_EDGE=3, A_CAT3=4, A_CAT2R=5 };
enum { E_STORE=0, E_RELU=1, E_BIAS=2, E_BIASRELU=3 };

template<int AM, int EM>
__global__ __launch_bounds__(256)
void gemm_nt(const float* __restrict__ A0, const float* __restrict__ A1,
             const float* __restrict__ A2, const float* __restrict__ W,
             const float* __restrict__ bias, float* __restrict__ C,
             int M, int N, int K, int lda,
             const int* __restrict__ i0, const int* __restrict__ i1,
             const int* __restrict__ i2)
{
    __shared__ float As[128][33];
    __shared__ float Bs[128][33];
    const int t  = threadIdx.x;
    const int tx = t & 15, ty = t >> 4;
    const int row0 = blockIdx.y * 128, col0 = blockIdx.x * 128;

    float acc[8][8] = {};

    for (int k0 = 0; k0 < K; k0 += 32) {
        #pragma unroll
        for (int i = 0; i < 16; i++) {
            int idx = t + i * 256;
            int r = idx >> 5, kk = idx & 31;
            int grow = row0 + r, gk = k0 + kk;
            float v;
            if (AM == A_PLAIN) {
                v = A0[(size_t)grow * lda + gk];
            } else if (AM == A_ADD) {
                v = A0[(size_t)grow * lda + gk] + A1[(size_t)grow * lda + gk];
            } else if (AM == A_RELUB) {
                v = relu_(A0[(size_t)grow * lda + gk] + A1[gk]);
            } else if (AM == A_EDGE) {
                if (gk < NEMB)            v = A0[(size_t)i0[grow] * NEMB + gk];
                else if (gk < NEMB+REMB)  v = A1[(size_t)i1[grow] * REMB + (gk - NEMB)];
                else                      v = A0[(size_t)i2[grow] * NEMB + (gk - NEMB - REMB)];
            } else if (AM == A_CAT3) {
                if (gk < HD)        v = A0[(size_t)grow * HD + gk];
                else if (gk < 2*HD) v = A1[(size_t)grow * HD + gk - HD];
                else                v = A2[(size_t)grow * HD + gk - 2*HD];
            } else { // A_CAT2R
                v = (gk < HD) ? relu_(A0[(size_t)grow * HD + gk])
                              : relu_(A1[(size_t)grow * HD + gk - HD]);
            }
            As[r][kk] = v;
        }
        #pragma unroll
        for (int i = 0; i < 16; i++) {
            int idx = t + i * 256;
            int r = idx >> 5, kk = idx & 31;
            Bs[r][kk] = W[(size_t)(col0 + r) * K + k0 + kk];
        }
        __syncthreads();
        #pragma unroll
        for (int k = 0; k < 32; k++) {
            float a[8], b[8];
            #pragma unroll
            for (int i = 0; i < 8; i++) a[i] = As[ty*8+i][k];
            #pragma unroll
            for (int j = 0; j < 8; j++) b[j] = Bs[tx*8+j][k];
            #pragma unroll
            for (int i = 0; i < 8; i++)
                #pragma unroll
                for (int j = 0; j < 8; j++)
                    acc[i][j] = fmaf(a[i], b[j], acc[i][j]);
        }
        __syncthreads();
    }
    #pragma unroll
    for (int i = 0; i < 8; i++) {
        int r = row0 + ty*8 + i;
        #pragma unroll
        for (int j = 0; j < 8; j++) {
            int c = col0 + tx*8 + j;
            float v = acc[i][j];
            if (EM == E_BIAS || EM == E_BIASRELU) v += bias[c];
            if (EM == E_RELU || EM == E_BIASRELU) v = relu_(v);
            C[(size_t)r * N + c] = v;
        }
    }
}

// ------- fused: me = (MODE? relu(ie+tmp[src]) : ie); s=sigmoid(tanh(me@W1L^T+term[b]).W2);
//                atomicAdd(agg[dst], me*s)  -- msg_edge never materialized -------
template<int MODE>
__global__ __launch_bounds__(256)
void attn_seg_fused(const float* __restrict__ ie, const float* __restrict__ tmp,
                    const int* __restrict__ src, const int* __restrict__ dst,
                    const float* __restrict__ W1, const float* __restrict__ W2,
                    const float* __restrict__ term, float* __restrict__ agg)
{
    __shared__ float As[64][33];
    __shared__ float Ws[256][33];
    const int t = threadIdx.x;
    const int tx = t & 31, ty = t >> 5;   // tx: 32 col-groups of 8; ty: 8 row-groups of 8
    const int r0 = blockIdx.x * 64;

    float acc[8][8] = {};

    for (int k0 = 0; k0 < HD; k0 += 32) {
        #pragma unroll
        for (int i = 0; i < 8; i++) {           // 64*32/256
            int idx = t + i * 256;
            int r = idx >> 5, kk = idx & 31;
            int e = r0 + r, gk = k0 + kk;
            float v = ie[(size_t)e * HD + gk];
            if (MODE) v = relu_(v + tmp[(size_t)src[e] * HD + gk]);
            As[r][kk] = v;
        }
        #pragma unroll
        for (int i = 0; i < 32; i++) {          // 256*32/256
            int idx = t + i * 256;
            int r = idx >> 5, kk = idx & 31;
            Ws[r][kk] = W1[(size_t)r * 512 + k0 + kk];   // left half of [256,512]
        }
        __syncthreads();
        #pragma unroll
        for (int k = 0; k < 32; k++) {
            float a[8], b[8];
            #pragma unroll
            for (int i = 0; i < 8; i++) a[i] = As[ty*8+i][k];
            #pragma unroll
            for (int j = 0; j < 8; j++) b[j] = Ws[tx*8+j][k];
            #pragma unroll
            for (int i = 0; i < 8; i++)
                #pragma unroll
                for (int j = 0; j < 8; j++)
                    acc[i][j] = fmaf(a[i], b[j], acc[i][j]);
        }
        __syncthreads();
    }
    #pragma unroll
    for (int i = 0; i < 8; i++) {
        int r = r0 + ty*8 + i;
        int b = r / Eg;
        float p = 0.f;
        #pragma unroll
        for (int j = 0; j < 8; j++) {
            int c = tx*8 + j;
            float v = tanhf(acc[i][j] + term[b*HD + c]);
            p += v * W2[c];
        }
        #pragma unroll
        for (int off = 1; off < 32; off <<= 1) p += __shfl_xor(p, off);
        float s = sigm_(p);
        int dr = dst[r];
        int sr = MODE ? src[r] : 0;
        #pragma unroll
        for (int j = 0; j < 8; j++) {
            int c = tx*8 + j;
            float me = ie[(size_t)r * HD + c];
            if (MODE) me = relu_(me + tmp[(size_t)sr * HD + c]);
            atomicAdd(&agg[(size_t)dr * HD + c], me * s);
        }
    }
}

// ------------- per-graph attention bias terms -------------
__global__ __launch_bounds__(256)
void term_kernel(const float* __restrict__ mn, const float* __restrict__ tgt_rel,
                 const float* __restrict__ Wa1, const float* __restrict__ Wd1,
                 const int* __restrict__ srcn, const int* __restrict__ tgtn,
                 float* __restrict__ term)
{
    __shared__ float Gs[HD];
    int b = blockIdx.x % Bg;
    int which = blockIdx.x / Bg;
    int c = threadIdx.x;
    float g;
    if (which == 0)
        g = mn[(size_t)srcn[b]*HD + c] + tgt_rel[b*HD + c] - mn[(size_t)tgtn[b]*HD + c];
    else
        g = tgt_rel[b*HD + c];
    Gs[c] = g;
    __syncthreads();
    const float* W = (which == 0) ? Wa1 : (Wd1 + (size_t)(which-1)*HD*512);
    float p = 0.f;
    for (int k = 0; k < HD; k++)
        p = fmaf(Gs[k], W[(size_t)c*512 + 256 + k], p);
    term[(size_t)which*Bg*HD + b*HD + c] = p;
}

__global__ void tgtrel_kernel(const float* __restrict__ rel_emb, const int* __restrict__ batch_rel,
                              float* __restrict__ tgt_rel)
{
    int b = blockIdx.x, c = threadIdx.x;
    tgt_rel[b*HD + c] = rel_emb[(size_t)batch_rel[b]*REMB + c];
}

__global__ void zero_kernel(float4* __restrict__ p)
{
    p[(size_t)blockIdx.x * 256 + threadIdx.x] = float4{0.f, 0.f, 0.f, 0.f};
}

__global__ void h0_kernel(const float* __restrict__ agg2, float* __restrict__ h0)
{
    int b = blockIdx.x, c = threadIdx.x;
    float m = -1e30f;
    for (int n = 0; n < Nn; n++)
        m = fmaxf(m, agg2[((size_t)b*Nn + n)*HD + c]);
    h0[b*HD + c] = m;
}

// ------------- GRU recurrent matmul: gh[d][b][n] = h_prev[b] . w_hh[n] -------------
__global__ __launch_bounds__(256)
void gru_gh(const float* __restrict__ outf, const float* __restrict__ outb,
            const float* __restrict__ h0,
            const float* __restrict__ whf, const float* __restrict__ whb,
            float* __restrict__ gh, int t)
{
    __shared__ float hs[32][260];
    int bi = blockIdx.x;          // 96 = 2 dirs * 12 colblocks * 4 rowblocks
    int d  = bi / 48;
    int rem = bi % 48;
    int cb = rem / 4;
    int rb = rem % 4;
    int r0 = rb * 32;
    int n0 = cb * 64;

    const float* hp; size_t hstride;
    if (t == 0)      { hp = h0;                                  hstride = HD; }
    else if (d == 0) { hp = outf + (size_t)(t-1)*HD;             hstride = (size_t)Nn*HD; }
    else             { int tb = Nn-1-t; hp = outb + (size_t)(tb+1)*HD; hstride = (size_t)Nn*HD; }

    int tid = threadIdx.x;
    #pragma unroll
    for (int i = 0; i < 32; i++) {
        int idx = tid + i * 256;
        int r = idx >> 8, k = idx & 255;
        hs[r][k] = hp[(size_t)(r0 + r) * hstride + k];
    }
    __syncthreads();

    const float* W = (d ? whb : whf) + (size_t)n0 * HD;
    int cg = tid & 31;
    int rg = tid >> 5;
    float acc[4][2] = {};
    for (int k = 0; k < HD; k += 4) {
        float4 w0 = *(const float4*)&W[(size_t)(cg*2 + 0)*HD + k];
        float4 w1 = *(const float4*)&W[(size_t)(cg*2 + 1)*HD + k];
        #pragma unroll
        for (int i = 0; i < 4; i++) {
            float4 h4 = *(const float4*)&hs[rg*4 + i][k];
            acc[i][0] += h4.x*w0.x + h4.y*w0.y + h4.z*w0.z + h4.w*w0.w;
            acc[i][1] += h4.x*w1.x + h4.y*w1.y + h4.z*w1.z + h4.w*w1.w;
        }
    }
    #pragma unroll
    for (int i = 0; i < 4; i++) {
        int b = r0 + rg*4 + i;
        #pragma unroll
        for (int j = 0; j < 2; j++)
            gh[(size_t)d*Bg*768 + (size_t)b*768 + n0 + cg*2 + j] = acc[i][j];
    }
}

__global__ void gru_gates(const float* __restrict__ gi_f, const float* __restrict__ gi_b,
                          const float* __restrict__ gh, const float* __restrict__ h0,
                          const float* __restrict__ bhf, const float* __restrict__ bhb,
                          float* __restrict__ outf, float* __restrict__ outb, int t)
{
    int gid = blockIdx.x * 256 + threadIdx.x;   // 2*128*256
    int h = gid & 255;
    int b = (gid >> 8) & 127;
    int d = gid >> 15;

    const float* gi; const float* bh; float* out; int trow; const float* hp;
    if (d == 0) {
        gi = gi_f; bh = bhf; out = outf; trow = t;
        hp = (t == 0) ? h0 + b*HD : outf + ((size_t)b*Nn + t - 1)*HD;
    } else {
        int tb = Nn - 1 - t;
        gi = gi_b; bh = bhb; out = outb; trow = tb;
        hp = (t == 0) ? h0 + b*HD : outb + ((size_t)b*Nn + tb + 1)*HD;
    }
    size_t girow = ((size_t)b*Nn + trow) * 768;
    size_t ghrow = ((size_t)d*Bg + b) * 768;
    float hprev = hp[h];
    float r = sigm_(gi[girow + h]        + gh[ghrow + h]        + bh[h]);
    float z = sigm_(gi[girow + 256 + h]  + gh[ghrow + 256 + h]  + bh[256 + h]);
    float n = tanhf(gi[girow + 512 + h]  + r * (gh[ghrow + 512 + h] + bh[512 + h]));
    out[((size_t)b*Nn + trow)*HD + h] = (1.f - z)*n + z*hprev;
}

__global__ __launch_bounds__(256)
void final_kernel(const float* __restrict__ atom_h, const float* __restrict__ tgt_rel,
                  const int* __restrict__ srcn, const int* __restrict__ tgtn,
                  const float* __restrict__ Wl, const float* __restrict__ bl,
                  float* __restrict__ out)
{
    __shared__ float red[4];
    int b = blockIdx.x, c = threadIdx.x;
    float v = tanhf(atom_h[(size_t)srcn[b]*HD + c] + tgt_rel[b*HD + c]
                    - atom_h[(size_t)tgtn[b]*HD + c]);
    float p = v * Wl[c];
    #pragma unroll
    for (int off = 1; off < 64; off <<= 1) p += __shfl_xor(p, off);
    int wv = c >> 6;
    if ((c & 63) == 0) red[wv] = p;
    __syncthreads();
    if (c == 0) out[b] = red[0] + red[1] + red[2] + red[3] + bl[0];
}

extern "C" void kernel_launch(void* const* d_in, const int* in_sizes, int n_in,
                              void* d_out, int out_size, void* d_ws, size_t ws_size,
                              hipStream_t stream)
{
    const float* node_feat = (const float*)d_in[0];
    const float* rel_emb   = (const float*)d_in[1];
    const float* W_i_node  = (const float*)d_in[2];
    const float* W_i_edge  = (const float*)d_in[3];
    const float* Wa1       = (const float*)d_in[4];
    const float* Wa2       = (const float*)d_in[5];
    const float* W_h_atom  = (const float*)d_in[6];
    const float* W_h_bond  = (const float*)d_in[7];
    const float* Wd1       = (const float*)d_in[8];
    const float* Wd2       = (const float*)d_in[9];
    const float* W_comm    = (const float*)d_in[10];
    const float* gru_bias  = (const float*)d_in[11];
    const float* w_ih_f    = (const float*)d_in[12];
    const float* w_hh_f    = (const float*)d_in[13];
    const float* b_ih_f    = (const float*)d_in[14];
    const float* b_hh_f    = (const float*)d_in[15];
    const float* w_ih_b    = (const float*)d_in[16];
    const float* w_hh_b    = (const float*)d_in[17];
    const float* b_ih_b    = (const float*)d_in[18];
    const float* b_hh_b    = (const float*)d_in[19];
    const float* W_o       = (const float*)d_in[20];
    const float* b_o       = (const float*)d_in[21];
    const float* W_lin1    = (const float*)d_in[22];
    const float* b_lin1    = (const float*)d_in[23];
    const int* edge_src  = (const int*)d_in[24];
    const int* edge_dst  = (const int*)d_in[25];
    const int* edge_rel  = (const int*)d_in[26];
    const int* batch_rel = (const int*)d_in[27];
    const int* src_node  = (const int*)d_in[28];
    const int* tgt_node  = (const int*)d_in[29];
    float* out = (float*)d_out;

    float* ws = (float*)d_ws;
    size_t off = 0;
    auto alloc = [&](size_t n){ float* p = ws + off; off += n; return p; };
    float* tgt_rel    = alloc((size_t)Bg*HD);
    float* term       = alloc((size_t)3*Bg*HD);
    float* input_node = alloc((size_t)TNODE*HD);
    float* mn_a       = alloc((size_t)TNODE*HD);
    float* mn_b       = alloc((size_t)TNODE*HD);
    float* agg        = alloc((size_t)TNODE*HD);
    float* h0v        = alloc((size_t)Bg*HD);
    float* gh         = alloc((size_t)2*Bg*768);
    float* input_edge = alloc((size_t)TEDGE*HD);   // total ~151 MiB
    // aliases (lifetimes disjoint):
    float* agg2  = mn_a;                              // after fused2 (tmp2 dead)
    float* gi_f  = input_edge;                        // after fused2 (input_edge dead)
    float* gi_b  = input_edge + (size_t)TNODE*768;
    float* out_f = input_edge + (size_t)2*TNODE*768;  // 19.66M + 6.55M = 26.21M fits
    float* out_b = out_f + (size_t)TNODE*HD;
    float* atom_h = input_node;                       // after W_comm GEMM

    tgtrel_kernel<<<Bg, 256, 0, stream>>>(rel_emb, batch_rel, tgt_rel);

    // input_node = relu(node_feat @ W_i_node^T)
    gemm_nt<A_PLAIN, E_RELU><<<dim3(HD/128, TNODE/128), 256, 0, stream>>>(
        node_feat, nullptr, nullptr, W_i_node, nullptr, input_node,
        TNODE, HD, NEMB, NEMB, nullptr, nullptr, nullptr);

    // input_edge = relu(edge_feat @ W_i_edge^T)
    gemm_nt<A_EDGE, E_RELU><<<dim3(HD/128, TEDGE/128), 256, 0, stream>>>(
        node_feat, rel_emb, nullptr, W_i_edge, nullptr, input_edge,
        TEDGE, HD, 512, 0, edge_src, edge_rel, edge_dst);

    term_kernel<<<3*Bg, 256, 0, stream>>>(input_node, tgt_rel, Wa1, Wd1,
                                          src_node, tgt_node, term);

    // ---- input attention + segsum (fused) ----
    zero_kernel<<<TNODE*HD/4/256, 256, 0, stream>>>((float4*)agg);
    attn_seg_fused<0><<<TEDGE/64, 256, 0, stream>>>(input_edge, nullptr, edge_src,
        edge_dst, Wa1, Wa2, term, agg);

    const float* mn_cur = input_node;
    float* bufs[2] = {mn_a, mn_b};
    for (int d = 0; d < 2; d++) {
        float* mn_next = bufs[d];
        float* tmp     = bufs[1-d];
        gemm_nt<A_ADD, E_RELU><<<dim3(2, TNODE/128), 256, 0, stream>>>(
            mn_cur, agg, nullptr, W_h_atom + (size_t)d*HD*HD, nullptr, mn_next,
            TNODE, HD, HD, HD, nullptr, nullptr, nullptr);
        gemm_nt<A_PLAIN, E_STORE><<<dim3(2, TNODE/128), 256, 0, stream>>>(
            mn_next, nullptr, nullptr, W_h_bond + (size_t)d*HD*HD, nullptr, tmp,
            TNODE, HD, HD, HD, nullptr, nullptr, nullptr);
        zero_kernel<<<TNODE*HD/4/256, 256, 0, stream>>>((float4*)agg);
        attn_seg_fused<1><<<TEDGE/64, 256, 0, stream>>>(input_edge, tmp, edge_src,
            edge_dst, Wd1 + (size_t)d*HD*512, Wd2 + (size_t)d*HD,
            term + (size_t)(1+d)*Bg*HD, agg);
        mn_cur = mn_next;
    }

    // agg2 = concat([agg, mn, input_node]) @ W_comm^T   (agg2 aliases mn_a)
    gemm_nt<A_CAT3, E_STORE><<<dim3(2, TNODE/128), 256, 0, stream>>>(
        agg, (const float*)mn_cur, input_node, W_comm, nullptr, agg2,
        TNODE, HD, 3*HD, 0, nullptr, nullptr, nullptr);

    h0_kernel<<<Bg, 256, 0, stream>>>(agg2, h0v);

    // gi = relu(agg2 + gru_bias) @ w_ih^T + b_ih   (both directions)
    gemm_nt<A_RELUB, E_BIAS><<<dim3(768/128, TNODE/128), 256, 0, stream>>>(
        agg2, gru_bias, nullptr, w_ih_f, b_ih_f, gi_f,
        TNODE, 768, HD, HD, nullptr, nullptr, nullptr);
    gemm_nt<A_RELUB, E_BIAS><<<dim3(768/128, TNODE/128), 256, 0, stream>>>(
        agg2, gru_bias, nullptr, w_ih_b, b_ih_b, gi_b,
        TNODE, 768, HD, HD, nullptr, nullptr, nullptr);

    for (int t = 0; t < Nn; t++) {
        gru_gh<<<96, 256, 0, stream>>>(out_f, out_b, h0v, w_hh_f, w_hh_b, gh, t);
        gru_gates<<<256, 256, 0, stream>>>(gi_f, gi_b, gh, h0v, b_hh_f, b_hh_b,
                                           out_f, out_b, t);
    }

    // atom_h = relu(relu(concat(out_f,out_b)) @ W_o^T + b_o)
    gemm_nt<A_CAT2R, E_BIASRELU><<<dim3(2, TNODE/128), 256, 0, stream>>>(
        out_f, out_b, nullptr, W_o, b_o, atom_h,
        TNODE, HD, 2*HD, 0, nullptr, nullptr, nullptr);

    final_kernel<<<Bg, 256, 0, stream>>>(atom_h, tgt_rel, src_node, tgt_node,
                                         W_lin1, b_lin1, out);
}

// Round 3
// 3912.982 us; speedup vs baseline: 1.7165x; 1.7165x over previous
//
#include <hip/hip_runtime.h>
#include <cstddef>

#define Bg 128
#define Nn 100
#define Eg 800
#define TNODE 12800
#define TEDGE 102400
#define HD 256
#define NEMB 128
#define REMB 256

__device__ __forceinline__ float relu_(float x){ return x > 0.f ? x : 0.f; }
__device__ __forceinline__ float sigm_(float x){ return 1.f/(1.f + __expf(-x)); }
__device__ __forceinline__ float4 ld4(const float* p){ return *(const float4*)p; }
__device__ __forceinline__ void st4(float* p, float4 v){ *(float4*)p = v; }
__device__ __forceinline__ float4 add4(float4 a, float4 b){
    return float4{a.x+b.x, a.y+b.y, a.z+b.z, a.w+b.w};
}
__device__ __forceinline__ float4 relu4(float4 a){
    return float4{relu_(a.x), relu_(a.y), relu_(a.z), relu_(a.w)};
}

// ---------------- tiled f32 GEMM:  C[M,N] = epi(A[M,K] @ W[N,K]^T) ----------------
// k-major LDS (stride 132 ≡ 4 mod 32: transposed stores 2-way max, b128 reads conflict-free)
enum { A_PLAIN=0, A_ADD=1, A_RELUB=2, A_EDGE=3, A_CAT3=4, A_CAT2R=5 };
enum { E_STORE=0, E_RELU=1, E_BIAS=2, E_BIASRELU=3 };

template<int AM, int EM>
__global__ __launch_bounds__(256, 3)
void gemm_nt(const float* __restrict__ A0, const float* __restrict__ A1,
             const float* __restrict__ A2, const float* __restrict__ W,
             const float* __restrict__ bias, float* __restrict__ C,
             int M, int N, int K, int lda,
             const int* __restrict__ i0, const int* __restrict__ i1,
             const int* __restrict__ i2)
{
    __shared__ float As[32][132];
    __shared__ float Bs[32][132];
    const int t  = threadIdx.x;
    const int tx = t & 15, ty = t >> 4;      // 16 x 16 thread grid
    const int kc = t & 7;                    // float4 chunk along k
    const int lr = t >> 3;                   // 0..31
    const int row0 = blockIdx.y * 128, col0 = blockIdx.x * 128;

    float acc[8][8] = {};   // rows: ty*4+i (+64), cols: tx*4+j (+64)

    for (int k0 = 0; k0 < K; k0 += 32) {
        const int gk = k0 + kc * 4;
        // ---- A tile: 128 rows x 32 k, transposed store ----
        #pragma unroll
        for (int ri = 0; ri < 4; ri++) {
            int row = lr + 32 * ri;
            int grow = row0 + row;
            float4 v;
            if (AM == A_PLAIN) {
                v = ld4(A0 + (size_t)grow * lda + gk);
            } else if (AM == A_ADD) {
                v = add4(ld4(A0 + (size_t)grow * lda + gk),
                         ld4(A1 + (size_t)grow * lda + gk));
            } else if (AM == A_RELUB) {
                v = relu4(add4(ld4(A0 + (size_t)grow * lda + gk), ld4(A1 + gk)));
            } else if (AM == A_EDGE) {
                if (gk < NEMB)            v = ld4(A0 + (size_t)i0[grow] * NEMB + gk);
                else if (gk < NEMB+REMB)  v = ld4(A1 + (size_t)i1[grow] * REMB + (gk - NEMB));
                else                      v = ld4(A0 + (size_t)i2[grow] * NEMB + (gk - NEMB - REMB));
            } else if (AM == A_CAT3) {
                if (gk < HD)        v = ld4(A0 + (size_t)grow * HD + gk);
                else if (gk < 2*HD) v = ld4(A1 + (size_t)grow * HD + gk - HD);
                else                v = ld4(A2 + (size_t)grow * HD + gk - 2*HD);
            } else { // A_CAT2R
                v = (gk < HD) ? relu4(ld4(A0 + (size_t)grow * HD + gk))
                              : relu4(ld4(A1 + (size_t)grow * HD + gk - HD));
            }
            As[kc*4+0][row] = v.x; As[kc*4+1][row] = v.y;
            As[kc*4+2][row] = v.z; As[kc*4+3][row] = v.w;
        }
        // ---- W tile: 128 N-rows x 32 k, transposed store ----
        #pragma unroll
        for (int ri = 0; ri < 4; ri++) {
            int wr = lr + 32 * ri;
            float4 v = ld4(W + (size_t)(col0 + wr) * K + gk);
            Bs[kc*4+0][wr] = v.x; Bs[kc*4+1][wr] = v.y;
            Bs[kc*4+2][wr] = v.z; Bs[kc*4+3][wr] = v.w;
        }
        __syncthreads();
        #pragma unroll
        for (int k = 0; k < 32; k++) {
            float4 a0 = ld4(&As[k][tx ? tx*0 + ty*4 : ty*4]);   // &As[k][ty*4]
            float4 a1 = ld4(&As[k][ty*4 + 64]);
            float4 b0 = ld4(&Bs[k][tx*4]);
            float4 b1 = ld4(&Bs[k][tx*4 + 64]);
            float av[8] = {a0.x,a0.y,a0.z,a0.w, a1.x,a1.y,a1.z,a1.w};
            float bv[8] = {b0.x,b0.y,b0.z,b0.w, b1.x,b1.y,b1.z,b1.w};
            #pragma unroll
            for (int i = 0; i < 8; i++)
                #pragma unroll
                for (int j = 0; j < 8; j++)
                    acc[i][j] = fmaf(av[i], bv[j], acc[i][j]);
        }
        __syncthreads();
    }
    #pragma unroll
    for (int ih = 0; ih < 2; ih++) {
        #pragma unroll
        for (int i = 0; i < 4; i++) {
            int r = row0 + ih*64 + ty*4 + i;
            #pragma unroll
            for (int jh = 0; jh < 2; jh++) {
                int c = col0 + jh*64 + tx*4;
                float4 v = {acc[ih*4+i][jh*4+0], acc[ih*4+i][jh*4+1],
                            acc[ih*4+i][jh*4+2], acc[ih*4+i][jh*4+3]};
                if (EM == E_BIAS || EM == E_BIASRELU) v = add4(v, ld4(bias + c));
                if (EM == E_RELU || EM == E_BIASRELU) v = relu4(v);
                st4(C + (size_t)r * N + c, v);
            }
        }
    }
}

// ------- fused: me = (MODE? relu(ie+tmp[src]) : ie); s=sigmoid(tanh(me@W1L^T+term[b]).W2);
//                atomicAdd(agg[dst], me*s) -------
template<int MODE>
__global__ __launch_bounds__(256, 3)
void attn_seg_fused(const float* __restrict__ ie, const float* __restrict__ tmp,
                    const int* __restrict__ src, const int* __restrict__ dst,
                    const float* __restrict__ W1, const float* __restrict__ W2,
                    const float* __restrict__ term, float* __restrict__ agg)
{
    __shared__ float As[32][68];
    __shared__ float Ws[32][260];
    const int t = threadIdx.x;
    const int tx = t & 31, ty = t >> 5;    // 32 col-groups x 8 row-groups
    const int kc = t & 7;
    const int lr = t >> 3;                 // 0..31
    const int r0 = blockIdx.x * 64;

    float acc[8][8] = {};   // rows ty*4+i (+32), cols tx*4+j (+128)

    for (int k0 = 0; k0 < HD; k0 += 32) {
        const int gk = k0 + kc * 4;
        #pragma unroll
        for (int ri = 0; ri < 2; ri++) {
            int row = lr + 32 * ri;
            int e = r0 + row;
            float4 v = ld4(ie + (size_t)e * HD + gk);
            if (MODE) v = relu4(add4(v, ld4(tmp + (size_t)src[e] * HD + gk)));
            As[kc*4+0][row] = v.x; As[kc*4+1][row] = v.y;
            As[kc*4+2][row] = v.z; As[kc*4+3][row] = v.w;
        }
        #pragma unroll
        for (int ri = 0; ri < 8; ri++) {
            int wr = lr + 32 * ri;
            float4 v = ld4(W1 + (size_t)wr * 512 + gk);   // left half of [256,512]
            Ws[kc*4+0][wr] = v.x; Ws[kc*4+1][wr] = v.y;
            Ws[kc*4+2][wr] = v.z; Ws[kc*4+3][wr] = v.w;
        }
        __syncthreads();
        #pragma unroll
        for (int k = 0; k < 32; k++) {
            float4 a0 = ld4(&As[k][ty*4]);
            float4 a1 = ld4(&As[k][ty*4 + 32]);
            float4 b0 = ld4(&Ws[k][tx*4]);
            float4 b1 = ld4(&Ws[k][tx*4 + 128]);
            float av[8] = {a0.x,a0.y,a0.z,a0.w, a1.x,a1.y,a1.z,a1.w};
            float bv[8] = {b0.x,b0.y,b0.z,b0.w, b1.x,b1.y,b1.z,b1.w};
            #pragma unroll
            for (int i = 0; i < 8; i++)
                #pragma unroll
                for (int j = 0; j < 8; j++)
                    acc[i][j] = fmaf(av[i], bv[j], acc[i][j]);
        }
        __syncthreads();
    }
    #pragma unroll
    for (int ih = 0; ih < 2; ih++) {
        #pragma unroll
        for (int i = 0; i < 4; i++) {
            int er = r0 + ih*32 + ty*4 + i;
            int g = er / Eg;
            float p = 0.f;
            #pragma unroll
            for (int jh = 0; jh < 2; jh++) {
                #pragma unroll
                for (int j = 0; j < 4; j++) {
                    int c = jh*128 + tx*4 + j;
                    float v = tanhf(acc[ih*4+i][jh*4+j] + term[g*HD + c]);
                    p += v * W2[c];
                }
            }
            #pragma unroll
            for (int off = 1; off < 32; off <<= 1) p += __shfl_xor(p, off);
            float s = sigm_(p);
            int dr = dst[er];
            int sr = MODE ? src[er] : 0;
            #pragma unroll
            for (int jh = 0; jh < 2; jh++) {
                int c = jh*128 + tx*4;
                float4 me = ld4(ie + (size_t)er * HD + c);
                if (MODE) me = relu4(add4(me, ld4(tmp + (size_t)sr * HD + c)));
                atomicAdd(&agg[(size_t)dr * HD + c + 0], me.x * s);
                atomicAdd(&agg[(size_t)dr * HD + c + 1], me.y * s);
                atomicAdd(&agg[(size_t)dr * HD + c + 2], me.z * s);
                atomicAdd(&agg[(size_t)dr * HD + c + 3], me.w * s);
            }
        }
    }
}

// ------------- per-graph attention bias terms -------------
__global__ __launch_bounds__(256)
void term_kernel(const float* __restrict__ mn, const float* __restrict__ tgt_rel,
                 const float* __restrict__ Wa1, const float* __restrict__ Wd1,
                 const int* __restrict__ srcn, const int* __restrict__ tgtn,
                 float* __restrict__ term)
{
    __shared__ float Gs[HD];
    int b = blockIdx.x % Bg;
    int which = blockIdx.x / Bg;
    int c = threadIdx.x;
    float g;
    if (which == 0)
        g = mn[(size_t)srcn[b]*HD + c] + tgt_rel[b*HD + c] - mn[(size_t)tgtn[b]*HD + c];
    else
        g = tgt_rel[b*HD + c];
    Gs[c] = g;
    __syncthreads();
    const float* W = (which == 0) ? Wa1 : (Wd1 + (size_t)(which-1)*HD*512);
    float p = 0.f;
    for (int k = 0; k < HD; k += 4) {
        float4 w = ld4(W + (size_t)c*512 + 256 + k);
        p = fmaf(Gs[k], w.x, p); p = fmaf(Gs[k+1], w.y, p);
        p = fmaf(Gs[k+2], w.z, p); p = fmaf(Gs[k+3], w.w, p);
    }
    term[(size_t)which*Bg*HD + b*HD + c] = p;
}

__global__ void tgtrel_kernel(const float* __restrict__ rel_emb, const int* __restrict__ batch_rel,
                              float* __restrict__ tgt_rel)
{
    int b = blockIdx.x, c = threadIdx.x;
    tgt_rel[b*HD + c] = rel_emb[(size_t)batch_rel[b]*REMB + c];
}

__global__ void zero_kernel(float4* __restrict__ p)
{
    p[(size_t)blockIdx.x * 256 + threadIdx.x] = float4{0.f, 0.f, 0.f, 0.f};
}

__global__ void h0_kernel(const float* __restrict__ agg2, float* __restrict__ h0)
{
    int b = blockIdx.x, c = threadIdx.x;
    float m = -1e30f;
    for (int n = 0; n < Nn; n++)
        m = fmaxf(m, agg2[((size_t)b*Nn + n)*HD + c]);
    h0[b*HD + c] = m;
}

// ------------- transpose w_hh to k-major: whT[d][k][768] -------------
__global__ void whT_kernel(const float* __restrict__ whf, const float* __restrict__ whb,
                           float* __restrict__ whT)
{
    int d = blockIdx.x >> 8, k = blockIdx.x & 255;
    const float* w = d ? whb : whf;
    int c = threadIdx.x;   // 768
    whT[((size_t)d*256 + k)*768 + c] = w[(size_t)c*256 + k];
}

// ------------- fused GRU step: gh + gates, 1 launch/step -------------
__global__ __launch_bounds__(256)
void gru_step(const float* __restrict__ gi_f, const float* __restrict__ gi_b,
              const float* __restrict__ whT,
              const float* __restrict__ bhf, const float* __restrict__ bhb,
              const float* __restrict__ h0,
              float* __restrict__ outf, float* __restrict__ outb, int t)
{
    __shared__ float hs[4][260];
    int blk = blockIdx.x;                // 64 = 2 dirs * 32
    int d = blk >> 5, r0 = (blk & 31) * 4;
    int tid = threadIdx.x;

    {   // load 4 rows of h_prev
        int row = tid >> 6, c = (tid & 63) * 4;
        const float* hp;
        if (t == 0)       hp = h0 + (size_t)(r0 + row) * HD;
        else if (d == 0)  hp = outf + ((size_t)(r0 + row) * Nn + (t - 1)) * HD;
        else              hp = outb + ((size_t)(r0 + row) * Nn + (Nn - t)) * HD;
        st4(&hs[row][c], ld4(hp + c));
    }
    __syncthreads();

    int h = tid;
    const float* wt = whT + (size_t)d * 256 * 768;
    float ar[4] = {}, az[4] = {}, an[4] = {};
    for (int k = 0; k < 256; k++) {
        float wr = wt[(size_t)k*768 + h];
        float wz = wt[(size_t)k*768 + 256 + h];
        float wn = wt[(size_t)k*768 + 512 + h];
        #pragma unroll
        for (int rI = 0; rI < 4; rI++) {
            float hk = hs[rI][k];
            ar[rI] = fmaf(hk, wr, ar[rI]);
            az[rI] = fmaf(hk, wz, az[rI]);
            an[rI] = fmaf(hk, wn, an[rI]);
        }
    }
    const float* gi = d ? gi_b : gi_f;
    const float* bh = d ? bhb : bhf;
    float* outp = d ? outb : outf;
    int trow = (d == 0) ? t : (Nn - 1 - t);
    #pragma unroll
    for (int rI = 0; rI < 4; rI++) {
        int b = r0 + rI;
        size_t girow = ((size_t)b * Nn + trow) * 768;
        float hprev = hs[rI][h];
        float r = sigm_(gi[girow + h]       + ar[rI] + bh[h]);
        float z = sigm_(gi[girow + 256 + h] + az[rI] + bh[256 + h]);
        float n = tanhf(gi[girow + 512 + h] + r * (an[rI] + bh[512 + h]));
        outp[((size_t)b * Nn + trow) * HD + h] = (1.f - z) * n + z * hprev;
    }
}

__global__ __launch_bounds__(256)
void final_kernel(const float* __restrict__ atom_h, const float* __restrict__ tgt_rel,
                  const int* __restrict__ srcn, const int* __restrict__ tgtn,
                  const float* __restrict__ Wl, const float* __restrict__ bl,
                  float* __restrict__ out)
{
    __shared__ float red[4];
    int b = blockIdx.x, c = threadIdx.x;
    float v = tanhf(atom_h[(size_t)srcn[b]*HD + c] + tgt_rel[b*HD + c]
                    - atom_h[(size_t)tgtn[b]*HD + c]);
    float p = v * Wl[c];
    #pragma unroll
    for (int off = 1; off < 64; off <<= 1) p += __shfl_xor(p, off);
    int wv = c >> 6;
    if ((c & 63) == 0) red[wv] = p;
    __syncthreads();
    if (c == 0) out[b] = red[0] + red[1] + red[2] + red[3] + bl[0];
}

extern "C" void kernel_launch(void* const* d_in, const int* in_sizes, int n_in,
                              void* d_out, int out_size, void* d_ws, size_t ws_size,
                              hipStream_t stream)
{
    const float* node_feat = (const float*)d_in[0];
    const float* rel_emb   = (const float*)d_in[1];
    const float* W_i_node  = (const float*)d_in[2];
    const float* W_i_edge  = (const float*)d_in[3];
    const float* Wa1       = (const float*)d_in[4];
    const float* Wa2       = (const float*)d_in[5];
    const float* W_h_atom  = (const float*)d_in[6];
    const float* W_h_bond  = (const float*)d_in[7];
    const float* Wd1       = (const float*)d_in[8];
    const float* Wd2       = (const float*)d_in[9];
    const float* W_comm    = (const float*)d_in[10];
    const float* gru_bias  = (const float*)d_in[11];
    const float* w_ih_f    = (const float*)d_in[12];
    const float* w_hh_f    = (const float*)d_in[13];
    const float* b_ih_f    = (const float*)d_in[14];
    const float* b_hh_f    = (const float*)d_in[15];
    const float* w_ih_b    = (const float*)d_in[16];
    const float* w_hh_b    = (const float*)d_in[17];
    const float* b_ih_b    = (const float*)d_in[18];
    const float* b_hh_b    = (const float*)d_in[19];
    const float* W_o       = (const float*)d_in[20];
    const float* b_o       = (const float*)d_in[21];
    const float* W_lin1    = (const float*)d_in[22];
    const float* b_lin1    = (const float*)d_in[23];
    const int* edge_src  = (const int*)d_in[24];
    const int* edge_dst  = (const int*)d_in[25];
    const int* edge_rel  = (const int*)d_in[26];
    const int* batch_rel = (const int*)d_in[27];
    const int* src_node  = (const int*)d_in[28];
    const int* tgt_node  = (const int*)d_in[29];
    float* out = (float*)d_out;

    float* ws = (float*)d_ws;
    size_t off = 0;
    auto alloc = [&](size_t n){ float* p = ws + off; off += n; return p; };
    float* tgt_rel    = alloc((size_t)Bg*HD);
    float* term       = alloc((size_t)3*Bg*HD);
    float* input_node = alloc((size_t)TNODE*HD);
    float* mn_a       = alloc((size_t)TNODE*HD);
    float* mn_b       = alloc((size_t)TNODE*HD);
    float* agg        = alloc((size_t)TNODE*HD);
    float* h0v        = alloc((size_t)Bg*HD);
    float* whT        = alloc((size_t)2*256*768);
    float* input_edge = alloc((size_t)TEDGE*HD);
    // aliases (lifetimes disjoint):
    float* agg2  = mn_a;                              // after last fused attn
    float* gi_f  = input_edge;                        // after last fused attn
    float* gi_b  = input_edge + (size_t)TNODE*768;
    float* out_f = input_edge + (size_t)2*TNODE*768;
    float* out_b = out_f + (size_t)TNODE*HD;
    float* atom_h = input_node;                       // after W_comm GEMM

    tgtrel_kernel<<<Bg, 256, 0, stream>>>(rel_emb, batch_rel, tgt_rel);
    whT_kernel<<<512, 768, 0, stream>>>(w_hh_f, w_hh_b, whT);

    // input_node = relu(node_feat @ W_i_node^T)
    gemm_nt<A_PLAIN, E_RELU><<<dim3(HD/128, TNODE/128), 256, 0, stream>>>(
        node_feat, nullptr, nullptr, W_i_node, nullptr, input_node,
        TNODE, HD, NEMB, NEMB, nullptr, nullptr, nullptr);

    // input_edge = relu(edge_feat @ W_i_edge^T)
    gemm_nt<A_EDGE, E_RELU><<<dim3(HD/128, TEDGE/128), 256, 0, stream>>>(
        node_feat, rel_emb, nullptr, W_i_edge, nullptr, input_edge,
        TEDGE, HD, 512, 0, edge_src, edge_rel, edge_dst);

    term_kernel<<<3*Bg, 256, 0, stream>>>(input_node, tgt_rel, Wa1, Wd1,
                                          src_node, tgt_node, term);

    // ---- input attention + segsum (fused) ----
    zero_kernel<<<TNODE*HD/4/256, 256, 0, stream>>>((float4*)agg);
    attn_seg_fused<0><<<TEDGE/64, 256, 0, stream>>>(input_edge, nullptr, edge_src,
        edge_dst, Wa1, Wa2, term, agg);

    const float* mn_cur = input_node;
    float* bufs[2] = {mn_a, mn_b};
    for (int d = 0; d < 2; d++) {
        float* mn_next = bufs[d];
        float* tmp     = bufs[1-d];
        gemm_nt<A_ADD, E_RELU><<<dim3(2, TNODE/128), 256, 0, stream>>>(
            mn_cur, agg, nullptr, W_h_atom + (size_t)d*HD*HD, nullptr, mn_next,
            TNODE, HD, HD, HD, nullptr, nullptr, nullptr);
        gemm_nt<A_PLAIN, E_STORE><<<dim3(2, TNODE/128), 256, 0, stream>>>(
            mn_next, nullptr, nullptr, W_h_bond + (size_t)d*HD*HD, nullptr, tmp,
            TNODE, HD, HD, HD, nullptr, nullptr, nullptr);
        zero_kernel<<<TNODE*HD/4/256, 256, 0, stream>>>((float4*)agg);
        attn_seg_fused<1><<<TEDGE/64, 256, 0, stream>>>(input_edge, tmp, edge_src,
            edge_dst, Wd1 + (size_t)d*HD*512, Wd2 + (size_t)d*HD,
            term + (size_t)(1+d)*Bg*HD, agg);
        mn_cur = mn_next;
    }

    // agg2 = concat([agg, mn, input_node]) @ W_comm^T   (agg2 aliases mn_a)
    gemm_nt<A_CAT3, E_STORE><<<dim3(2, TNODE/128), 256, 0, stream>>>(
        agg, (const float*)mn_cur, input_node, W_comm, nullptr, agg2,
        TNODE, HD, 3*HD, 0, nullptr, nullptr, nullptr);

    h0_kernel<<<Bg, 256, 0, stream>>>(agg2, h0v);

    // gi = relu(agg2 + gru_bias) @ w_ih^T + b_ih   (both directions)
    gemm_nt<A_RELUB, E_BIAS><<<dim3(768/128, TNODE/128), 256, 0, stream>>>(
        agg2, gru_bias, nullptr, w_ih_f, b_ih_f, gi_f,
        TNODE, 768, HD, HD, nullptr, nullptr, nullptr);
    gemm_nt<A_RELUB, E_BIAS><<<dim3(768/128, TNODE/128), 256, 0, stream>>>(
        agg2, gru_bias, nullptr, w_ih_b, b_ih_b, gi_b,
        TNODE, 768, HD, HD, nullptr, nullptr, nullptr);

    for (int t = 0; t < Nn; t++) {
        gru_step<<<64, 256, 0, stream>>>(gi_f, gi_b, whT, b_hh_f, b_hh_b, h0v,
                                         out_f, out_b, t);
    }

    // atom_h = relu(relu(concat(out_f,out_b)) @ W_o^T + b_o)
    gemm_nt<A_CAT2R, E_BIASRELU><<<dim3(2, TNODE/128), 256, 0, stream>>>(
        out_f, out_b, nullptr, W_o, b_o, atom_h,
        TNODE, HD, 2*HD, 0, nullptr, nullptr, nullptr);

    final_kernel<<<Bg, 256, 0, stream>>>(atom_h, tgt_rel, src_node, tgt_node,
                                         W_lin1, b_lin1, out);
}

// Round 4
// 3163.763 us; speedup vs baseline: 2.1230x; 1.2368x over previous
//
#include <hip/hip_runtime.h>
#include <cstddef>

#define Bg 128
#define Nn 100
#define Eg 800
#define TNODE 12800
#define TEDGE 102400
#define HD 256
#define NEMB 128
#define REMB 256

__device__ __forceinline__ float relu_(float x){ return x > 0.f ? x : 0.f; }
__device__ __forceinline__ float sigm_(float x){ return 1.f/(1.f + __expf(-x)); }
__device__ __forceinline__ float4 ld4(const float* p){ return *(const float4*)p; }
__device__ __forceinline__ void st4(float* p, float4 v){ *(float4*)p = v; }
__device__ __forceinline__ float4 add4(float4 a, float4 b){
    return float4{a.x+b.x, a.y+b.y, a.z+b.z, a.w+b.w};
}
__device__ __forceinline__ float4 relu4(float4 a){
    return float4{relu_(a.x), relu_(a.y), relu_(a.z), relu_(a.w)};
}

// ---------------- tiled f32 GEMM:  C[M,N] = epi(A[M,K] @ W[N,K]^T) ----------------
enum { A_PLAIN=0, A_ADD=1, A_RELUB=2, A_EDGE=3, A_CAT3=4, A_CAT2R=5 };
enum { E_STORE=0, E_RELU=1, E_BIAS=2, E_BIASRELU=3 };

template<int AM, int EM>
__global__ __launch_bounds__(256, 3)
void gemm_nt(const float* __restrict__ A0, const float* __restrict__ A1,
             const float* __restrict__ A2, const float* __restrict__ W,
             const float* __restrict__ bias, float* __restrict__ C,
             int M, int N, int K, int lda,
             const int* __restrict__ i0, const int* __restrict__ i1,
             const int* __restrict__ i2)
{
    __shared__ float As[32][132];
    __shared__ float Bs[32][132];
    const int t  = threadIdx.x;
    const int tx = t & 15, ty = t >> 4;      // 16 x 16 thread grid
    const int kc = t & 7;                    // float4 chunk along k
    const int lr = t >> 3;                   // 0..31
    const int row0 = blockIdx.y * 128, col0 = blockIdx.x * 128;

    float acc[8][8] = {};

    for (int k0 = 0; k0 < K; k0 += 32) {
        const int gk = k0 + kc * 4;
        #pragma unroll
        for (int ri = 0; ri < 4; ri++) {
            int row = lr + 32 * ri;
            int grow = row0 + row;
            float4 v;
            if (AM == A_PLAIN) {
                v = ld4(A0 + (size_t)grow * lda + gk);
            } else if (AM == A_ADD) {
                v = add4(ld4(A0 + (size_t)grow * lda + gk),
                         ld4(A1 + (size_t)grow * lda + gk));
            } else if (AM == A_RELUB) {
                v = relu4(add4(ld4(A0 + (size_t)grow * lda + gk), ld4(A1 + gk)));
            } else if (AM == A_EDGE) {
                if (gk < NEMB)            v = ld4(A0 + (size_t)i0[grow] * NEMB + gk);
                else if (gk < NEMB+REMB)  v = ld4(A1 + (size_t)i1[grow] * REMB + (gk - NEMB));
                else                      v = ld4(A0 + (size_t)i2[grow] * NEMB + (gk - NEMB - REMB));
            } else if (AM == A_CAT3) {
                if (gk < HD)        v = ld4(A0 + (size_t)grow * HD + gk);
                else if (gk < 2*HD) v = ld4(A1 + (size_t)grow * HD + gk - HD);
                else                v = ld4(A2 + (size_t)grow * HD + gk - 2*HD);
            } else { // A_CAT2R
                v = (gk < HD) ? relu4(ld4(A0 + (size_t)grow * HD + gk))
                              : relu4(ld4(A1 + (size_t)grow * HD + gk - HD));
            }
            As[kc*4+0][row] = v.x; As[kc*4+1][row] = v.y;
            As[kc*4+2][row] = v.z; As[kc*4+3][row] = v.w;
        }
        #pragma unroll
        for (int ri = 0; ri < 4; ri++) {
            int wr = lr + 32 * ri;
            float4 v = ld4(W + (size_t)(col0 + wr) * K + gk);
            Bs[kc*4+0][wr] = v.x; Bs[kc*4+1][wr] = v.y;
            Bs[kc*4+2][wr] = v.z; Bs[kc*4+3][wr] = v.w;
        }
        __syncthreads();
        #pragma unroll
        for (int k = 0; k < 32; k++) {
            float4 a0 = ld4(&As[k][ty*4]);
            float4 a1 = ld4(&As[k][ty*4 + 64]);
            float4 b0 = ld4(&Bs[k][tx*4]);
            float4 b1 = ld4(&Bs[k][tx*4 + 64]);
            float av[8] = {a0.x,a0.y,a0.z,a0.w, a1.x,a1.y,a1.z,a1.w};
            float bv[8] = {b0.x,b0.y,b0.z,b0.w, b1.x,b1.y,b1.z,b1.w};
            #pragma unroll
            for (int i = 0; i < 8; i++)
                #pragma unroll
                for (int j = 0; j < 8; j++)
                    acc[i][j] = fmaf(av[i], bv[j], acc[i][j]);
        }
        __syncthreads();
    }
    #pragma unroll
    for (int ih = 0; ih < 2; ih++) {
        #pragma unroll
        for (int i = 0; i < 4; i++) {
            int r = row0 + ih*64 + ty*4 + i;
            #pragma unroll
            for (int jh = 0; jh < 2; jh++) {
                int c = col0 + jh*64 + tx*4;
                float4 v = {acc[ih*4+i][jh*4+0], acc[ih*4+i][jh*4+1],
                            acc[ih*4+i][jh*4+2], acc[ih*4+i][jh*4+3]};
                if (EM == E_BIAS || EM == E_BIASRELU) v = add4(v, ld4(bias + c));
                if (EM == E_RELU || EM == E_BIASRELU) v = relu4(v);
                st4(C + (size_t)r * N + c, v);
            }
        }
    }
}

// ------- attention scale only: s[e] = sigmoid( tanh(me@W1L^T + term[g]) . W2 ),
//         me = (MODE? relu(ie+tmp[src]) : ie)  — no scatter, no me materialization -------
template<int MODE>
__global__ __launch_bounds__(256, 3)
void attn_s(const float* __restrict__ ie, const float* __restrict__ tmp,
            const int* __restrict__ src,
            const float* __restrict__ W1, const float* __restrict__ W2,
            const float* __restrict__ term, float* __restrict__ sbuf)
{
    __shared__ float As[32][68];
    __shared__ float Ws[32][260];
    const int t = threadIdx.x;
    const int tx = t & 31, ty = t >> 5;    // 32 col-groups x 8 row-groups
    const int kc = t & 7;
    const int lr = t >> 3;
    const int r0 = blockIdx.x * 64;

    float acc[8][8] = {};

    for (int k0 = 0; k0 < HD; k0 += 32) {
        const int gk = k0 + kc * 4;
        #pragma unroll
        for (int ri = 0; ri < 2; ri++) {
            int row = lr + 32 * ri;
            int e = r0 + row;
            float4 v = ld4(ie + (size_t)e * HD + gk);
            if (MODE) v = relu4(add4(v, ld4(tmp + (size_t)src[e] * HD + gk)));
            As[kc*4+0][row] = v.x; As[kc*4+1][row] = v.y;
            As[kc*4+2][row] = v.z; As[kc*4+3][row] = v.w;
        }
        #pragma unroll
        for (int ri = 0; ri < 8; ri++) {
            int wr = lr + 32 * ri;
            float4 v = ld4(W1 + (size_t)wr * 512 + gk);   // left half of [256,512]
            Ws[kc*4+0][wr] = v.x; Ws[kc*4+1][wr] = v.y;
            Ws[kc*4+2][wr] = v.z; Ws[kc*4+3][wr] = v.w;
        }
        __syncthreads();
        #pragma unroll
        for (int k = 0; k < 32; k++) {
            float4 a0 = ld4(&As[k][ty*4]);
            float4 a1 = ld4(&As[k][ty*4 + 32]);
            float4 b0 = ld4(&Ws[k][tx*4]);
            float4 b1 = ld4(&Ws[k][tx*4 + 128]);
            float av[8] = {a0.x,a0.y,a0.z,a0.w, a1.x,a1.y,a1.z,a1.w};
            float bv[8] = {b0.x,b0.y,b0.z,b0.w, b1.x,b1.y,b1.z,b1.w};
            #pragma unroll
            for (int i = 0; i < 8; i++)
                #pragma unroll
                for (int j = 0; j < 8; j++)
                    acc[i][j] = fmaf(av[i], bv[j], acc[i][j]);
        }
        __syncthreads();
    }
    #pragma unroll
    for (int ih = 0; ih < 2; ih++) {
        #pragma unroll
        for (int i = 0; i < 4; i++) {
            int er = r0 + ih*32 + ty*4 + i;
            int g = er / Eg;
            float p = 0.f;
            #pragma unroll
            for (int jh = 0; jh < 2; jh++) {
                #pragma unroll
                for (int j = 0; j < 4; j++) {
                    int c = jh*128 + tx*4 + j;
                    float v = tanhf(acc[ih*4+i][jh*4+j] + term[g*HD + c]);
                    p += v * W2[c];
                }
            }
            #pragma unroll
            for (int off = 1; off < 32; off <<= 1) p += __shfl_xor(p, off);
            if (tx == 0) sbuf[er] = sigm_(p);
        }
    }
}

// ------- CSR-gather aggregation: agg[n] = sum_{e: dst[e]==n} me(e) * s[e] -------
template<int MODE>
__global__ __launch_bounds__(256)
void agg_gather(const float* __restrict__ ie, const float* __restrict__ tmp,
                const int* __restrict__ src, const int* __restrict__ rowptr,
                const int* __restrict__ eidx, const float* __restrict__ s,
                float* __restrict__ agg)
{
    int node = blockIdx.x * 4 + (threadIdx.x >> 6);
    int c = (threadIdx.x & 63) * 4;
    float4 acc{0.f, 0.f, 0.f, 0.f};
    int beg = rowptr[node], end = rowptr[node + 1];
    for (int i = beg; i < end; i++) {
        int e = eidx[i];
        float4 v = ld4(ie + (size_t)e * HD + c);
        if (MODE) v = relu4(add4(v, ld4(tmp + (size_t)src[e] * HD + c)));
        float sc = s[e];
        acc.x += v.x * sc; acc.y += v.y * sc;
        acc.z += v.z * sc; acc.w += v.w * sc;
    }
    st4(agg + (size_t)node * HD + c, acc);
}

// ------------- CSR build (graph static per launch) -------------
__global__ void zeroi_kernel(int* __restrict__ p)
{
    p[blockIdx.x * 256 + threadIdx.x] = 0;
}
__global__ void csr_count(const int* __restrict__ dst, int* __restrict__ cnt)
{
    int e = blockIdx.x * 256 + threadIdx.x;
    atomicAdd(&cnt[dst[e]], 1);
}
__global__ void csr_scan(const int* __restrict__ cnt, int* __restrict__ rowptr)
{
    __shared__ int ws[4];
    __shared__ int carry;
    int tid = threadIdx.x;
    if (tid == 0) carry = 0;
    __syncthreads();
    for (int i = 0; i < TNODE; i += 256) {
        int v = cnt[i + tid];
        int x = v;
        #pragma unroll
        for (int off = 1; off < 64; off <<= 1) {
            int y = __shfl_up(x, off);
            if ((tid & 63) >= off) x += y;
        }
        if ((tid & 63) == 63) ws[tid >> 6] = x;
        __syncthreads();
        int add = carry;
        int w = tid >> 6;
        for (int j = 0; j < w; j++) add += ws[j];
        rowptr[i + tid] = add + x - v;      // exclusive
        __syncthreads();
        if (tid == 255) carry = add + x;
        __syncthreads();
    }
    if (tid == 0) rowptr[TNODE] = carry;
}
__global__ void csr_fill(const int* __restrict__ dst, const int* __restrict__ rowptr,
                         int* __restrict__ fillc, int* __restrict__ eidx)
{
    int e = blockIdx.x * 256 + threadIdx.x;
    int d = dst[e];
    int slot = rowptr[d] + atomicAdd(&fillc[d], 1);
    eidx[slot] = e;
}

// ------------- per-graph attention bias terms -------------
__global__ __launch_bounds__(256)
void term_kernel(const float* __restrict__ mn, const float* __restrict__ tgt_rel,
                 const float* __restrict__ Wa1, const float* __restrict__ Wd1,
                 const int* __restrict__ srcn, const int* __restrict__ tgtn,
                 float* __restrict__ term)
{
    __shared__ float Gs[HD];
    int b = blockIdx.x % Bg;
    int which = blockIdx.x / Bg;
    int c = threadIdx.x;
    float g;
    if (which == 0)
        g = mn[(size_t)srcn[b]*HD + c] + tgt_rel[b*HD + c] - mn[(size_t)tgtn[b]*HD + c];
    else
        g = tgt_rel[b*HD + c];
    Gs[c] = g;
    __syncthreads();
    const float* W = (which == 0) ? Wa1 : (Wd1 + (size_t)(which-1)*HD*512);
    float p = 0.f;
    for (int k = 0; k < HD; k += 4) {
        float4 w = ld4(W + (size_t)c*512 + 256 + k);
        p = fmaf(Gs[k], w.x, p); p = fmaf(Gs[k+1], w.y, p);
        p = fmaf(Gs[k+2], w.z, p); p = fmaf(Gs[k+3], w.w, p);
    }
    term[(size_t)which*Bg*HD + b*HD + c] = p;
}

__global__ void tgtrel_kernel(const float* __restrict__ rel_emb, const int* __restrict__ batch_rel,
                              float* __restrict__ tgt_rel)
{
    int b = blockIdx.x, c = threadIdx.x;
    tgt_rel[b*HD + c] = rel_emb[(size_t)batch_rel[b]*REMB + c];
}

__global__ void h0_kernel(const float* __restrict__ agg2, float* __restrict__ h0)
{
    int b = blockIdx.x, c = threadIdx.x;
    float m = -1e30f;
    for (int n = 0; n < Nn; n++)
        m = fmaxf(m, agg2[((size_t)b*Nn + n)*HD + c]);
    h0[b*HD + c] = m;
}

// ------------- transpose w_hh to k-major: whT[d][k][768] -------------
__global__ void whT_kernel(const float* __restrict__ whf, const float* __restrict__ whb,
                           float* __restrict__ whT)
{
    int d = blockIdx.x >> 8, k = blockIdx.x & 255;
    const float* w = d ? whb : whf;
    int c = threadIdx.x;
    whT[((size_t)d*256 + k)*768 + c] = w[(size_t)c*256 + k];
}

// ------------- whole GRU in one launch: 64 blocks x 4 independent sequences -------------
__global__ __launch_bounds__(256)
void gru_all(const float* __restrict__ gi_f, const float* __restrict__ gi_b,
             const float* __restrict__ whT,
             const float* __restrict__ bhf, const float* __restrict__ bhb,
             const float* __restrict__ h0,
             float* __restrict__ outf, float* __restrict__ outb)
{
    __shared__ float hs[4][260];
    int blk = blockIdx.x;
    int d = blk >> 5, r0 = (blk & 31) * 4;
    int tid = threadIdx.x;

    {
        int row = tid >> 6, c = (tid & 63) * 4;
        st4(&hs[row][c], ld4(h0 + (size_t)(r0 + row) * HD + c));
    }
    const float* wt = whT + (size_t)d * 256 * 768;
    const float* gi = d ? gi_b : gi_f;
    const float* bh = d ? bhb : bhf;
    float* outp = d ? outb : outf;
    float bhr = bh[tid], bhz = bh[256 + tid], bhn = bh[512 + tid];

    for (int t = 0; t < Nn; t++) {
        __syncthreads();
        float ar[4] = {}, az[4] = {}, an[4] = {};
        for (int k = 0; k < 256; k += 4) {
            float4 hv[4];
            #pragma unroll
            for (int rI = 0; rI < 4; rI++) hv[rI] = ld4(&hs[rI][k]);
            #pragma unroll
            for (int kk = 0; kk < 4; kk++) {
                float wr = wt[(size_t)(k+kk)*768 + tid];
                float wz = wt[(size_t)(k+kk)*768 + 256 + tid];
                float wn = wt[(size_t)(k+kk)*768 + 512 + tid];
                #pragma unroll
                for (int rI = 0; rI < 4; rI++) {
                    float hk = ((const float*)&hv[rI])[kk];
                    ar[rI] = fmaf(hk, wr, ar[rI]);
                    az[rI] = fmaf(hk, wz, az[rI]);
                    an[rI] = fmaf(hk, wn, an[rI]);
                }
            }
        }
        int trow = d ? (Nn - 1 - t) : t;
        float nh[4];
        #pragma unroll
        for (int rI = 0; rI < 4; rI++) {
            size_t girow = ((size_t)(r0 + rI) * Nn + trow) * 768;
            float hprev = hs[rI][tid];
            float r = sigm_(gi[girow + tid]       + ar[rI] + bhr);
            float z = sigm_(gi[girow + 256 + tid] + az[rI] + bhz);
            float n = tanhf(gi[girow + 512 + tid] + r * (an[rI] + bhn));
            nh[rI] = (1.f - z) * n + z * hprev;
            outp[((size_t)(r0 + rI) * Nn + trow) * HD + tid] = nh[rI];
        }
        __syncthreads();
        #pragma unroll
        for (int rI = 0; rI < 4; rI++) hs[rI][tid] = nh[rI];
    }
}

__global__ __launch_bounds__(256)
void final_kernel(const float* __restrict__ atom_h, const float* __restrict__ tgt_rel,
                  const int* __restrict__ srcn, const int* __restrict__ tgtn,
                  const float* __restrict__ Wl, const float* __restrict__ bl,
                  float* __restrict__ out)
{
    __shared__ float red[4];
    int b = blockIdx.x, c = threadIdx.x;
    float v = tanhf(atom_h[(size_t)srcn[b]*HD + c] + tgt_rel[b*HD + c]
                    - atom_h[(size_t)tgtn[b]*HD + c]);
    float p = v * Wl[c];
    #pragma unroll
    for (int off = 1; off < 64; off <<= 1) p += __shfl_xor(p, off);
    int wv = c >> 6;
    if ((c & 63) == 0) red[wv] = p;
    __syncthreads();
    if (c == 0) out[b] = red[0] + red[1] + red[2] + red[3] + bl[0];
}

extern "C" void kernel_launch(void* const* d_in, const int* in_sizes, int n_in,
                              void* d_out, int out_size, void* d_ws, size_t ws_size,
                              hipStream_t stream)
{
    const float* node_feat = (const float*)d_in[0];
    const float* rel_emb   = (const float*)d_in[1];
    const float* W_i_node  = (const float*)d_in[2];
    const float* W_i_edge  = (const float*)d_in[3];
    const float* Wa1       = (const float*)d_in[4];
    const float* Wa2       = (const float*)d_in[5];
    const float* W_h_atom  = (const float*)d_in[6];
    const float* W_h_bond  = (const float*)d_in[7];
    const float* Wd1       = (const float*)d_in[8];
    const float* Wd2       = (const float*)d_in[9];
    const float* W_comm    = (const float*)d_in[10];
    const float* gru_bias  = (const float*)d_in[11];
    const float* w_ih_f    = (const float*)d_in[12];
    const float* w_hh_f    = (const float*)d_in[13];
    const float* b_ih_f    = (const float*)d_in[14];
    const float* b_hh_f    = (const float*)d_in[15];
    const float* w_ih_b    = (const float*)d_in[16];
    const float* w_hh_b    = (const float*)d_in[17];
    const float* b_ih_b    = (const float*)d_in[18];
    const float* b_hh_b    = (const float*)d_in[19];
    const float* W_o       = (const float*)d_in[20];
    const float* b_o       = (const float*)d_in[21];
    const float* W_lin1    = (const float*)d_in[22];
    const float* b_lin1    = (const float*)d_in[23];
    const int* edge_src  = (const int*)d_in[24];
    const int* edge_dst  = (const int*)d_in[25];
    const int* batch_rel = (const int*)d_in[27];
    const int* src_node  = (const int*)d_in[28];
    const int* tgt_node  = (const int*)d_in[29];
    const int* edge_rel  = (const int*)d_in[26];
    float* out = (float*)d_out;

    float* ws = (float*)d_ws;
    size_t off = 0;
    auto alloc = [&](size_t n){ float* p = ws + off; off += n; return p; };
    float* tgt_rel    = alloc((size_t)Bg*HD);
    float* term       = alloc((size_t)3*Bg*HD);
    float* input_node = alloc((size_t)TNODE*HD);
    float* mn_a       = alloc((size_t)TNODE*HD);
    float* mn_b       = alloc((size_t)TNODE*HD);
    float* agg        = alloc((size_t)TNODE*HD);
    float* h0v        = alloc((size_t)Bg*HD);
    float* whT        = alloc((size_t)2*256*768);
    float* sbuf       = alloc((size_t)TEDGE);
    int*   cnt        = (int*)alloc((size_t)TNODE);
    int*   fillc      = (int*)alloc((size_t)TNODE);
    int*   rowptr     = (int*)alloc((size_t)TNODE + 256);
    int*   eidx       = (int*)alloc((size_t)TEDGE);
    float* input_edge = alloc((size_t)TEDGE*HD);
    // aliases (lifetimes disjoint):
    float* agg2  = mn_a;                              // after last attn/gather
    float* gi_f  = input_edge;                        // after last attn/gather
    float* gi_b  = input_edge + (size_t)TNODE*768;
    float* out_f = input_edge + (size_t)2*TNODE*768;
    float* out_b = out_f + (size_t)TNODE*HD;
    float* atom_h = input_node;                       // after W_comm GEMM

    tgtrel_kernel<<<Bg, 256, 0, stream>>>(rel_emb, batch_rel, tgt_rel);
    whT_kernel<<<512, 768, 0, stream>>>(w_hh_f, w_hh_b, whT);

    // ---- CSR build (dst-sorted incidence) ----
    zeroi_kernel<<<2*TNODE/256, 256, 0, stream>>>(cnt);     // zeros cnt AND fillc (adjacent)
    csr_count<<<TEDGE/256, 256, 0, stream>>>(edge_dst, cnt);
    csr_scan<<<1, 256, 0, stream>>>(cnt, rowptr);
    csr_fill<<<TEDGE/256, 256, 0, stream>>>(edge_dst, rowptr, fillc, eidx);

    // input_node = relu(node_feat @ W_i_node^T)
    gemm_nt<A_PLAIN, E_RELU><<<dim3(HD/128, TNODE/128), 256, 0, stream>>>(
        node_feat, nullptr, nullptr, W_i_node, nullptr, input_node,
        TNODE, HD, NEMB, NEMB, nullptr, nullptr, nullptr);

    // input_edge = relu(edge_feat @ W_i_edge^T)
    gemm_nt<A_EDGE, E_RELU><<<dim3(HD/128, TEDGE/128), 256, 0, stream>>>(
        node_feat, rel_emb, nullptr, W_i_edge, nullptr, input_edge,
        TEDGE, HD, 512, 0, edge_src, edge_rel, edge_dst);

    term_kernel<<<3*Bg, 256, 0, stream>>>(input_node, tgt_rel, Wa1, Wd1,
                                          src_node, tgt_node, term);

    // ---- input attention scale + gather-aggregate ----
    attn_s<0><<<TEDGE/64, 256, 0, stream>>>(input_edge, nullptr, edge_src,
                                            Wa1, Wa2, term, sbuf);
    agg_gather<0><<<TNODE/4, 256, 0, stream>>>(input_edge, nullptr, edge_src,
                                               rowptr, eidx, sbuf, agg);

    const float* mn_cur = input_node;
    float* bufs[2] = {mn_a, mn_b};
    for (int d = 0; d < 2; d++) {
        float* mn_next = bufs[d];
        float* tmp     = bufs[1-d];
        gemm_nt<A_ADD, E_RELU><<<dim3(2, TNODE/128), 256, 0, stream>>>(
            mn_cur, agg, nullptr, W_h_atom + (size_t)d*HD*HD, nullptr, mn_next,
            TNODE, HD, HD, HD, nullptr, nullptr, nullptr);
        gemm_nt<A_PLAIN, E_STORE><<<dim3(2, TNODE/128), 256, 0, stream>>>(
            mn_next, nullptr, nullptr, W_h_bond + (size_t)d*HD*HD, nullptr, tmp,
            TNODE, HD, HD, HD, nullptr, nullptr, nullptr);
        attn_s<1><<<TEDGE/64, 256, 0, stream>>>(input_edge, tmp, edge_src,
            Wd1 + (size_t)d*HD*512, Wd2 + (size_t)d*HD, term + (size_t)(1+d)*Bg*HD, sbuf);
        agg_gather<1><<<TNODE/4, 256, 0, stream>>>(input_edge, tmp, edge_src,
            rowptr, eidx, sbuf, agg);
        mn_cur = mn_next;
    }

    // agg2 = concat([agg, mn, input_node]) @ W_comm^T   (agg2 aliases mn_a)
    gemm_nt<A_CAT3, E_STORE><<<dim3(2, TNODE/128), 256, 0, stream>>>(
        agg, (const float*)mn_cur, input_node, W_comm, nullptr, agg2,
        TNODE, HD, 3*HD, 0, nullptr, nullptr, nullptr);

    h0_kernel<<<Bg, 256, 0, stream>>>(agg2, h0v);

    // gi = relu(agg2 + gru_bias) @ w_ih^T + b_ih   (both directions)
    gemm_nt<A_RELUB, E_BIAS><<<dim3(768/128, TNODE/128), 256, 0, stream>>>(
        agg2, gru_bias, nullptr, w_ih_f, b_ih_f, gi_f,
        TNODE, 768, HD, HD, nullptr, nullptr, nullptr);
    gemm_nt<A_RELUB, E_BIAS><<<dim3(768/128, TNODE/128), 256, 0, stream>>>(
        agg2, gru_bias, nullptr, w_ih_b, b_ih_b, gi_b,
        TNODE, 768, HD, HD, nullptr, nullptr, nullptr);

    gru_all<<<64, 256, 0, stream>>>(gi_f, gi_b, whT, b_hh_f, b_hh_b, h0v,
                                    out_f, out_b);

    // atom_h = relu(relu(concat(out_f,out_b)) @ W_o^T + b_o)
    gemm_nt<A_CAT2R, E_BIASRELU><<<dim3(2, TNODE/128), 256, 0, stream>>>(
        out_f, out_b, nullptr, W_o, b_o, atom_h,
        TNODE, HD, 2*HD, 0, nullptr, nullptr, nullptr);

    final_kernel<<<Bg, 256, 0, stream>>>(atom_h, tgt_rel, src_node, tgt_node,
                                         W_lin1, b_lin1, out);
}

// Round 5
// 2425.010 us; speedup vs baseline: 2.7698x; 1.3046x over previous
//
#include <hip/hip_runtime.h>
#include <cstddef>

#define Bg 128
#define Nn 100
#define Eg 800
#define TNODE 12800
#define TEDGE 102400
#define HD 256
#define NEMB 128
#define REMB 256

__device__ __forceinline__ float relu_(float x){ return x > 0.f ? x : 0.f; }
__device__ __forceinline__ float sigm_(float x){ return 1.f/(1.f + __expf(-x)); }
__device__ __forceinline__ float4 ld4(const float* p){ return *(const float4*)p; }
__device__ __forceinline__ void st4(float* p, float4 v){ *(float4*)p = v; }
__device__ __forceinline__ float4 add4(float4 a, float4 b){
    return float4{a.x+b.x, a.y+b.y, a.z+b.z, a.w+b.w};
}
__device__ __forceinline__ float4 relu4(float4 a){
    return float4{relu_(a.x), relu_(a.y), relu_(a.z), relu_(a.w)};
}

// ---------------- tiled f32 GEMM:  C[M,N] = epi(A[M,K] @ W[N,K]^T) ----------------
enum { A_PLAIN=0, A_ADD=1, A_RELUB=2, A_EDGE=3, A_CAT3=4, A_CAT2R=5 };
enum { E_STORE=0, E_RELU=1, E_BIAS=2, E_BIASRELU=3 };

template<int AM, int EM>
__global__ __launch_bounds__(256, 3)
void gemm_nt(const float* __restrict__ A0, const float* __restrict__ A1,
             const float* __restrict__ A2, const float* __restrict__ W,
             const float* __restrict__ bias, float* __restrict__ C,
             int M, int N, int K, int lda,
             const int* __restrict__ i0, const int* __restrict__ i1,
             const int* __restrict__ i2)
{
    __shared__ float As[32][132];
    __shared__ float Bs[32][132];
    const int t  = threadIdx.x;
    const int tx = t & 15, ty = t >> 4;      // 16 x 16 thread grid
    const int kc = t & 7;                    // float4 chunk along k
    const int lr = t >> 3;                   // 0..31
    const int row0 = blockIdx.y * 128, col0 = blockIdx.x * 128;

    float acc[8][8] = {};

    for (int k0 = 0; k0 < K; k0 += 32) {
        const int gk = k0 + kc * 4;
        #pragma unroll
        for (int ri = 0; ri < 4; ri++) {
            int row = lr + 32 * ri;
            int grow = row0 + row;
            float4 v;
            if (AM == A_PLAIN) {
                v = ld4(A0 + (size_t)grow * lda + gk);
            } else if (AM == A_ADD) {
                v = add4(ld4(A0 + (size_t)grow * lda + gk),
                         ld4(A1 + (size_t)grow * lda + gk));
            } else if (AM == A_RELUB) {
                v = relu4(add4(ld4(A0 + (size_t)grow * lda + gk), ld4(A1 + gk)));
            } else if (AM == A_EDGE) {
                if (gk < NEMB)            v = ld4(A0 + (size_t)i0[grow] * NEMB + gk);
                else if (gk < NEMB+REMB)  v = ld4(A1 + (size_t)i1[grow] * REMB + (gk - NEMB));
                else                      v = ld4(A0 + (size_t)i2[grow] * NEMB + (gk - NEMB - REMB));
            } else if (AM == A_CAT3) {
                if (gk < HD)        v = ld4(A0 + (size_t)grow * HD + gk);
                else if (gk < 2*HD) v = ld4(A1 + (size_t)grow * HD + gk - HD);
                else                v = ld4(A2 + (size_t)grow * HD + gk - 2*HD);
            } else { // A_CAT2R
                v = (gk < HD) ? relu4(ld4(A0 + (size_t)grow * HD + gk))
                              : relu4(ld4(A1 + (size_t)grow * HD + gk - HD));
            }
            As[kc*4+0][row] = v.x; As[kc*4+1][row] = v.y;
            As[kc*4+2][row] = v.z; As[kc*4+3][row] = v.w;
        }
        #pragma unroll
        for (int ri = 0; ri < 4; ri++) {
            int wr = lr + 32 * ri;
            float4 v = ld4(W + (size_t)(col0 + wr) * K + gk);
            Bs[kc*4+0][wr] = v.x; Bs[kc*4+1][wr] = v.y;
            Bs[kc*4+2][wr] = v.z; Bs[kc*4+3][wr] = v.w;
        }
        __syncthreads();
        #pragma unroll
        for (int k = 0; k < 32; k++) {
            float4 a0 = ld4(&As[k][ty*4]);
            float4 a1 = ld4(&As[k][ty*4 + 64]);
            float4 b0 = ld4(&Bs[k][tx*4]);
            float4 b1 = ld4(&Bs[k][tx*4 + 64]);
            float av[8] = {a0.x,a0.y,a0.z,a0.w, a1.x,a1.y,a1.z,a1.w};
            float bv[8] = {b0.x,b0.y,b0.z,b0.w, b1.x,b1.y,b1.z,b1.w};
            #pragma unroll
            for (int i = 0; i < 8; i++)
                #pragma unroll
                for (int j = 0; j < 8; j++)
                    acc[i][j] = fmaf(av[i], bv[j], acc[i][j]);
        }
        __syncthreads();
    }
    #pragma unroll
    for (int ih = 0; ih < 2; ih++) {
        #pragma unroll
        for (int i = 0; i < 4; i++) {
            int r = row0 + ih*64 + ty*4 + i;
            #pragma unroll
            for (int jh = 0; jh < 2; jh++) {
                int c = col0 + jh*64 + tx*4;
                float4 v = {acc[ih*4+i][jh*4+0], acc[ih*4+i][jh*4+1],
                            acc[ih*4+i][jh*4+2], acc[ih*4+i][jh*4+3]};
                if (EM == E_BIAS || EM == E_BIASRELU) v = add4(v, ld4(bias + c));
                if (EM == E_RELU || EM == E_BIASRELU) v = relu4(v);
                st4(C + (size_t)r * N + c, v);
            }
        }
    }
}

// ------- attention scale only: s[e] = sigmoid( tanh(me@W1L^T + term[g]) . W2 ),
//         me = (MODE? relu(ie+tmp[src]) : ie) -------
template<int MODE>
__global__ __launch_bounds__(256, 3)
void attn_s(const float* __restrict__ ie, const float* __restrict__ tmp,
            const int* __restrict__ src,
            const float* __restrict__ W1, const float* __restrict__ W2,
            const float* __restrict__ term, float* __restrict__ sbuf)
{
    __shared__ float As[32][68];
    __shared__ float Ws[32][260];
    const int t = threadIdx.x;
    const int tx = t & 31, ty = t >> 5;
    const int kc = t & 7;
    const int lr = t >> 3;
    const int r0 = blockIdx.x * 64;

    float acc[8][8] = {};

    for (int k0 = 0; k0 < HD; k0 += 32) {
        const int gk = k0 + kc * 4;
        #pragma unroll
        for (int ri = 0; ri < 2; ri++) {
            int row = lr + 32 * ri;
            int e = r0 + row;
            float4 v = ld4(ie + (size_t)e * HD + gk);
            if (MODE) v = relu4(add4(v, ld4(tmp + (size_t)src[e] * HD + gk)));
            As[kc*4+0][row] = v.x; As[kc*4+1][row] = v.y;
            As[kc*4+2][row] = v.z; As[kc*4+3][row] = v.w;
        }
        #pragma unroll
        for (int ri = 0; ri < 8; ri++) {
            int wr = lr + 32 * ri;
            float4 v = ld4(W1 + (size_t)wr * 512 + gk);
            Ws[kc*4+0][wr] = v.x; Ws[kc*4+1][wr] = v.y;
            Ws[kc*4+2][wr] = v.z; Ws[kc*4+3][wr] = v.w;
        }
        __syncthreads();
        #pragma unroll
        for (int k = 0; k < 32; k++) {
            float4 a0 = ld4(&As[k][ty*4]);
            float4 a1 = ld4(&As[k][ty*4 + 32]);
            float4 b0 = ld4(&Ws[k][tx*4]);
            float4 b1 = ld4(&Ws[k][tx*4 + 128]);
            float av[8] = {a0.x,a0.y,a0.z,a0.w, a1.x,a1.y,a1.z,a1.w};
            float bv[8] = {b0.x,b0.y,b0.z,b0.w, b1.x,b1.y,b1.z,b1.w};
            #pragma unroll
            for (int i = 0; i < 8; i++)
                #pragma unroll
                for (int j = 0; j < 8; j++)
                    acc[i][j] = fmaf(av[i], bv[j], acc[i][j]);
        }
        __syncthreads();
    }
    #pragma unroll
    for (int ih = 0; ih < 2; ih++) {
        #pragma unroll
        for (int i = 0; i < 4; i++) {
            int er = r0 + ih*32 + ty*4 + i;
            int g = er / Eg;
            float p = 0.f;
            #pragma unroll
            for (int jh = 0; jh < 2; jh++) {
                #pragma unroll
                for (int j = 0; j < 4; j++) {
                    int c = jh*128 + tx*4 + j;
                    float v = tanhf(acc[ih*4+i][jh*4+j] + term[g*HD + c]);
                    p += v * W2[c];
                }
            }
            #pragma unroll
            for (int off = 1; off < 32; off <<= 1) p += __shfl_xor(p, off);
            if (tx == 0) sbuf[er] = sigm_(p);
        }
    }
}

// ------- CSR-gather aggregation: agg[n] = sum_{e: dst[e]==n} me(e) * s[e] -------
template<int MODE>
__global__ __launch_bounds__(256)
void agg_gather(const float* __restrict__ ie, const float* __restrict__ tmp,
                const int* __restrict__ src, const int* __restrict__ rowptr,
                const int* __restrict__ eidx, const float* __restrict__ s,
                float* __restrict__ agg)
{
    int node = blockIdx.x * 4 + (threadIdx.x >> 6);
    int c = (threadIdx.x & 63) * 4;
    float4 acc{0.f, 0.f, 0.f, 0.f};
    int beg = rowptr[node], end = rowptr[node + 1];
    for (int i = beg; i < end; i++) {
        int e = eidx[i];
        float4 v = ld4(ie + (size_t)e * HD + c);
        if (MODE) v = relu4(add4(v, ld4(tmp + (size_t)src[e] * HD + c)));
        float sc = s[e];
        acc.x += v.x * sc; acc.y += v.y * sc;
        acc.z += v.z * sc; acc.w += v.w * sc;
    }
    st4(agg + (size_t)node * HD + c, acc);
}

// ------------- CSR build (graph static per launch) -------------
__global__ void zeroi_kernel(int* __restrict__ p)
{
    p[blockIdx.x * 256 + threadIdx.x] = 0;
}
__global__ void csr_count(const int* __restrict__ dst, int* __restrict__ cnt)
{
    int e = blockIdx.x * 256 + threadIdx.x;
    atomicAdd(&cnt[dst[e]], 1);
}
__global__ void csr_scan(const int* __restrict__ cnt, int* __restrict__ rowptr)
{
    __shared__ int ws[4];
    __shared__ int carry;
    int tid = threadIdx.x;
    if (tid == 0) carry = 0;
    __syncthreads();
    for (int i = 0; i < TNODE; i += 256) {
        int v = cnt[i + tid];
        int x = v;
        #pragma unroll
        for (int off = 1; off < 64; off <<= 1) {
            int y = __shfl_up(x, off);
            if ((tid & 63) >= off) x += y;
        }
        if ((tid & 63) == 63) ws[tid >> 6] = x;
        __syncthreads();
        int add = carry;
        int w = tid >> 6;
        for (int j = 0; j < w; j++) add += ws[j];
        rowptr[i + tid] = add + x - v;      // exclusive
        __syncthreads();
        if (tid == 255) carry = add + x;
        __syncthreads();
    }
    if (tid == 0) rowptr[TNODE] = carry;
}
__global__ void csr_fill(const int* __restrict__ dst, const int* __restrict__ rowptr,
                         int* __restrict__ fillc, int* __restrict__ eidx)
{
    int e = blockIdx.x * 256 + threadIdx.x;
    int d = dst[e];
    int slot = rowptr[d] + atomicAdd(&fillc[d], 1);
    eidx[slot] = e;
}

// ------------- per-graph attention bias terms -------------
__global__ __launch_bounds__(256)
void term_kernel(const float* __restrict__ mn, const float* __restrict__ tgt_rel,
                 const float* __restrict__ Wa1, const float* __restrict__ Wd1,
                 const int* __restrict__ srcn, const int* __restrict__ tgtn,
                 float* __restrict__ term)
{
    __shared__ float Gs[HD];
    int b = blockIdx.x % Bg;
    int which = blockIdx.x / Bg;
    int c = threadIdx.x;
    float g;
    if (which == 0)
        g = mn[(size_t)srcn[b]*HD + c] + tgt_rel[b*HD + c] - mn[(size_t)tgtn[b]*HD + c];
    else
        g = tgt_rel[b*HD + c];
    Gs[c] = g;
    __syncthreads();
    const float* W = (which == 0) ? Wa1 : (Wd1 + (size_t)(which-1)*HD*512);
    float p = 0.f;
    for (int k = 0; k < HD; k += 4) {
        float4 w = ld4(W + (size_t)c*512 + 256 + k);
        p = fmaf(Gs[k], w.x, p); p = fmaf(Gs[k+1], w.y, p);
        p = fmaf(Gs[k+2], w.z, p); p = fmaf(Gs[k+3], w.w, p);
    }
    term[(size_t)which*Bg*HD + b*HD + c] = p;
}

__global__ void tgtrel_kernel(const float* __restrict__ rel_emb, const int* __restrict__ batch_rel,
                              float* __restrict__ tgt_rel)
{
    int b = blockIdx.x, c = threadIdx.x;
    tgt_rel[b*HD + c] = rel_emb[(size_t)batch_rel[b]*REMB + c];
}

__global__ void h0_kernel(const float* __restrict__ agg2, float* __restrict__ h0)
{
    int b = blockIdx.x, c = threadIdx.x;
    float m = -1e30f;
    for (int n = 0; n < Nn; n++)
        m = fmaxf(m, agg2[((size_t)b*Nn + n)*HD + c]);
    h0[b*HD + c] = m;
}

// ------------- transpose w_hh to k-major: whT[d][k][768] -------------
__global__ void whT_kernel(const float* __restrict__ whf, const float* __restrict__ whb,
                           float* __restrict__ whT)
{
    int d = blockIdx.x >> 8, k = blockIdx.x & 255;
    const float* w = d ? whb : whf;
    int c = threadIdx.x;
    whT[((size_t)d*256 + k)*768 + c] = w[(size_t)c*256 + k];
}

// ------------- whole GRU, one launch: 64 blocks x 1024 thr, 4-way k-split -------------
// block: (dir, 4 sequences). thread tid: kc=tid>>8 owns k in [kc*64, kc*64+64), h=tid&255.
__global__ __launch_bounds__(1024)
void gru_all(const float* __restrict__ gi_f, const float* __restrict__ gi_b,
             const float* __restrict__ whT,
             const float* __restrict__ bhf, const float* __restrict__ bhb,
             const float* __restrict__ h0,
             float* __restrict__ outf, float* __restrict__ outb)
{
    __shared__ float hs[4][256];
    __shared__ float part[4][12][256];   // [kc][g*4+seq][h]
    int blk = blockIdx.x;
    int d = blk >> 5, r0 = (blk & 31) * 4;
    int tid = threadIdx.x;
    int kc = tid >> 8, h = tid & 255;

    hs[kc][h] = h0[(size_t)(r0 + kc) * HD + h];

    const float* wt  = whT + (size_t)d * 256 * 768;
    const float* gi  = d ? gi_b : gi_f;
    const float* bh  = d ? bhb : bhf;
    float* outp      = d ? outb : outf;
    const float bhr = bh[h], bhz = bh[256 + h], bhn = bh[512 + h];
    const int kbase = kc * 64;
    __syncthreads();

    for (int t = 0; t < Nn; t++) {
        float ar[4] = {}, az[4] = {}, an[4] = {};
        #pragma unroll 8
        for (int k2 = 0; k2 < 64; k2++) {
            int k = kbase + k2;
            const float* wk = wt + (size_t)k * 768;
            float wr = wk[h], wz = wk[256 + h], wn = wk[512 + h];
            float hv0 = hs[0][k], hv1 = hs[1][k], hv2 = hs[2][k], hv3 = hs[3][k];
            ar[0] = fmaf(hv0, wr, ar[0]); az[0] = fmaf(hv0, wz, az[0]); an[0] = fmaf(hv0, wn, an[0]);
            ar[1] = fmaf(hv1, wr, ar[1]); az[1] = fmaf(hv1, wz, az[1]); an[1] = fmaf(hv1, wn, an[1]);
            ar[2] = fmaf(hv2, wr, ar[2]); az[2] = fmaf(hv2, wz, az[2]); an[2] = fmaf(hv2, wn, an[2]);
            ar[3] = fmaf(hv3, wr, ar[3]); az[3] = fmaf(hv3, wz, az[3]); an[3] = fmaf(hv3, wn, an[3]);
        }
        #pragma unroll
        for (int s = 0; s < 4; s++) {
            part[kc][s][h]     = ar[s];
            part[kc][4 + s][h] = az[s];
            part[kc][8 + s][h] = an[s];
        }
        __syncthreads();
        // epilogue: thread (kc as seq, h)
        int seq = kc;
        int trow = d ? (Nn - 1 - t) : t;
        float R = 0.f, Z = 0.f, NN = 0.f;
        #pragma unroll
        for (int q = 0; q < 4; q++) {
            R  += part[q][seq][h];
            Z  += part[q][4 + seq][h];
            NN += part[q][8 + seq][h];
        }
        size_t girow = ((size_t)(r0 + seq) * Nn + trow) * 768;
        float hprev = hs[seq][h];
        float r = sigm_(gi[girow + h]       + R + bhr);
        float z = sigm_(gi[girow + 256 + h] + Z + bhz);
        float n = tanhf(gi[girow + 512 + h] + r * (NN + bhn));
        float nh = (1.f - z) * n + z * hprev;
        outp[((size_t)(r0 + seq) * Nn + trow) * HD + h] = nh;
        __syncthreads();
        hs[seq][h] = nh;
        __syncthreads();
    }
}

__global__ __launch_bounds__(256)
void final_kernel(const float* __restrict__ atom_h, const float* __restrict__ tgt_rel,
                  const int* __restrict__ srcn, const int* __restrict__ tgtn,
                  const float* __restrict__ Wl, const float* __restrict__ bl,
                  float* __restrict__ out)
{
    __shared__ float red[4];
    int b = blockIdx.x, c = threadIdx.x;
    float v = tanhf(atom_h[(size_t)srcn[b]*HD + c] + tgt_rel[b*HD + c]
                    - atom_h[(size_t)tgtn[b]*HD + c]);
    float p = v * Wl[c];
    #pragma unroll
    for (int off = 1; off < 64; off <<= 1) p += __shfl_xor(p, off);
    int wv = c >> 6;
    if ((c & 63) == 0) red[wv] = p;
    __syncthreads();
    if (c == 0) out[b] = red[0] + red[1] + red[2] + red[3] + bl[0];
}

extern "C" void kernel_launch(void* const* d_in, const int* in_sizes, int n_in,
                              void* d_out, int out_size, void* d_ws, size_t ws_size,
                              hipStream_t stream)
{
    const float* node_feat = (const float*)d_in[0];
    const float* rel_emb   = (const float*)d_in[1];
    const float* W_i_node  = (const float*)d_in[2];
    const float* W_i_edge  = (const float*)d_in[3];
    const float* Wa1       = (const float*)d_in[4];
    const float* Wa2       = (const float*)d_in[5];
    const float* W_h_atom  = (const float*)d_in[6];
    const float* W_h_bond  = (const float*)d_in[7];
    const float* Wd1       = (const float*)d_in[8];
    const float* Wd2       = (const float*)d_in[9];
    const float* W_comm    = (const float*)d_in[10];
    const float* gru_bias  = (const float*)d_in[11];
    const float* w_ih_f    = (const float*)d_in[12];
    const float* w_hh_f    = (const float*)d_in[13];
    const float* b_ih_f    = (const float*)d_in[14];
    const float* b_hh_f    = (const float*)d_in[15];
    const float* w_ih_b    = (const float*)d_in[16];
    const float* w_hh_b    = (const float*)d_in[17];
    const float* b_ih_b    = (const float*)d_in[18];
    const float* b_hh_b    = (const float*)d_in[19];
    const float* W_o       = (const float*)d_in[20];
    const float* b_o       = (const float*)d_in[21];
    const float* W_lin1    = (const float*)d_in[22];
    const float* b_lin1    = (const float*)d_in[23];
    const int* edge_src  = (const int*)d_in[24];
    const int* edge_dst  = (const int*)d_in[25];
    const int* edge_rel  = (const int*)d_in[26];
    const int* batch_rel = (const int*)d_in[27];
    const int* src_node  = (const int*)d_in[28];
    const int* tgt_node  = (const int*)d_in[29];
    float* out = (float*)d_out;

    float* ws = (float*)d_ws;
    size_t off = 0;
    auto alloc = [&](size_t n){ float* p = ws + off; off += n; return p; };
    float* tgt_rel    = alloc((size_t)Bg*HD);
    float* term       = alloc((size_t)3*Bg*HD);
    float* input_node = alloc((size_t)TNODE*HD);
    float* mn_a       = alloc((size_t)TNODE*HD);
    float* mn_b       = alloc((size_t)TNODE*HD);
    float* agg        = alloc((size_t)TNODE*HD);
    float* h0v        = alloc((size_t)Bg*HD);
    float* whT        = alloc((size_t)2*256*768);
    float* sbuf       = alloc((size_t)TEDGE);
    int*   cnt        = (int*)alloc((size_t)TNODE);
    int*   fillc      = (int*)alloc((size_t)TNODE);
    int*   rowptr     = (int*)alloc((size_t)TNODE + 256);
    int*   eidx       = (int*)alloc((size_t)TEDGE);
    float* input_edge = alloc((size_t)TEDGE*HD);
    // aliases (lifetimes disjoint):
    float* agg2  = mn_a;                              // after last attn/gather
    float* gi_f  = input_edge;                        // after last attn/gather
    float* gi_b  = input_edge + (size_t)TNODE*768;
    float* out_f = input_edge + (size_t)2*TNODE*768;
    float* out_b = out_f + (size_t)TNODE*HD;
    float* atom_h = input_node;                       // after W_comm GEMM

    tgtrel_kernel<<<Bg, 256, 0, stream>>>(rel_emb, batch_rel, tgt_rel);
    whT_kernel<<<512, 768, 0, stream>>>(w_hh_f, w_hh_b, whT);

    // ---- CSR build (dst-sorted incidence) ----
    zeroi_kernel<<<2*TNODE/256, 256, 0, stream>>>(cnt);     // zeros cnt AND fillc (adjacent)
    csr_count<<<TEDGE/256, 256, 0, stream>>>(edge_dst, cnt);
    csr_scan<<<1, 256, 0, stream>>>(cnt, rowptr);
    csr_fill<<<TEDGE/256, 256, 0, stream>>>(edge_dst, rowptr, fillc, eidx);

    // input_node = relu(node_feat @ W_i_node^T)
    gemm_nt<A_PLAIN, E_RELU><<<dim3(HD/128, TNODE/128), 256, 0, stream>>>(
        node_feat, nullptr, nullptr, W_i_node, nullptr, input_node,
        TNODE, HD, NEMB, NEMB, nullptr, nullptr, nullptr);

    // input_edge = relu(edge_feat @ W_i_edge^T)
    gemm_nt<A_EDGE, E_RELU><<<dim3(HD/128, TEDGE/128), 256, 0, stream>>>(
        node_feat, rel_emb, nullptr, W_i_edge, nullptr, input_edge,
        TEDGE, HD, 512, 0, edge_src, edge_rel, edge_dst);

    term_kernel<<<3*Bg, 256, 0, stream>>>(input_node, tgt_rel, Wa1, Wd1,
                                          src_node, tgt_node, term);

    // ---- input attention scale + gather-aggregate ----
    attn_s<0><<<TEDGE/64, 256, 0, stream>>>(input_edge, nullptr, edge_src,
                                            Wa1, Wa2, term, sbuf);
    agg_gather<0><<<TNODE/4, 256, 0, stream>>>(input_edge, nullptr, edge_src,
                                               rowptr, eidx, sbuf, agg);

    const float* mn_cur = input_node;
    float* bufs[2] = {mn_a, mn_b};
    for (int d = 0; d < 2; d++) {
        float* mn_next = bufs[d];
        float* tmp     = bufs[1-d];
        gemm_nt<A_ADD, E_RELU><<<dim3(2, TNODE/128), 256, 0, stream>>>(
            mn_cur, agg, nullptr, W_h_atom + (size_t)d*HD*HD, nullptr, mn_next,
            TNODE, HD, HD, HD, nullptr, nullptr, nullptr);
        gemm_nt<A_PLAIN, E_STORE><<<dim3(2, TNODE/128), 256, 0, stream>>>(
            mn_next, nullptr, nullptr, W_h_bond + (size_t)d*HD*HD, nullptr, tmp,
            TNODE, HD, HD, HD, nullptr, nullptr, nullptr);
        attn_s<1><<<TEDGE/64, 256, 0, stream>>>(input_edge, tmp, edge_src,
            Wd1 + (size_t)d*HD*512, Wd2 + (size_t)d*HD, term + (size_t)(1+d)*Bg*HD, sbuf);
        agg_gather<1><<<TNODE/4, 256, 0, stream>>>(input_edge, tmp, edge_src,
            rowptr, eidx, sbuf, agg);
        mn_cur = mn_next;
    }

    // agg2 = concat([agg, mn, input_node]) @ W_comm^T   (agg2 aliases mn_a)
    gemm_nt<A_CAT3, E_STORE><<<dim3(2, TNODE/128), 256, 0, stream>>>(
        agg, (const float*)mn_cur, input_node, W_comm, nullptr, agg2,
        TNODE, HD, 3*HD, 0, nullptr, nullptr, nullptr);

    h0_kernel<<<Bg, 256, 0, stream>>>(agg2, h0v);

    // gi = relu(agg2 + gru_bias) @ w_ih^T + b_ih   (both directions)
    gemm_nt<A_RELUB, E_BIAS><<<dim3(768/128, TNODE/128), 256, 0, stream>>>(
        agg2, gru_bias, nullptr, w_ih_f, b_ih_f, gi_f,
        TNODE, 768, HD, HD, nullptr, nullptr, nullptr);
    gemm_nt<A_RELUB, E_BIAS><<<dim3(768/128, TNODE/128), 256, 0, stream>>>(
        agg2, gru_bias, nullptr, w_ih_b, b_ih_b, gi_b,
        TNODE, 768, HD, HD, nullptr, nullptr, nullptr);

    gru_all<<<64, 1024, 0, stream>>>(gi_f, gi_b, whT, b_hh_f, b_hh_b, h0v,
                                     out_f, out_b);

    // atom_h = relu(relu(concat(out_f,out_b)) @ W_o^T + b_o)
    gemm_nt<A_CAT2R, E_BIASRELU><<<dim3(2, TNODE/128), 256, 0, stream>>>(
        out_f, out_b, nullptr, W_o, b_o, atom_h,
        TNODE, HD, 2*HD, 0, nullptr, nullptr, nullptr);

    final_kernel<<<Bg, 256, 0, stream>>>(atom_h, tgt_rel, src_node, tgt_node,
                                         W_lin1, b_lin1, out);
}

// Round 6
// 1780.599 us; speedup vs baseline: 3.7722x; 1.3619x over previous
//
#include <hip/hip_runtime.h>
#include <cstddef>

#define Bg 128
#define Nn 100
#define Eg 800
#define TNODE 12800
#define TEDGE 102400
#define HD 256
#define NEMB 128
#define REMB 256

typedef short bf8 __attribute__((ext_vector_type(8)));
typedef short bf4 __attribute__((ext_vector_type(4)));
typedef float f4  __attribute__((ext_vector_type(4)));

__device__ __forceinline__ float relu_(float x){ return x > 0.f ? x : 0.f; }
__device__ __forceinline__ float sigm_(float x){ return 1.f/(1.f + __expf(-x)); }
__device__ __forceinline__ float4 ld4(const float* p){ return *(const float4*)p; }
__device__ __forceinline__ void st4(float* p, float4 v){ *(float4*)p = v; }
__device__ __forceinline__ float4 add4(float4 a, float4 b){
    return float4{a.x+b.x, a.y+b.y, a.z+b.z, a.w+b.w};
}
__device__ __forceinline__ float4 relu4(float4 a){
    return float4{relu_(a.x), relu_(a.y), relu_(a.z), relu_(a.w)};
}
__device__ __forceinline__ short f2bf(float f){
    unsigned u = __float_as_uint(f);
    u += 0x7fff + ((u >> 16) & 1);
    return (short)(u >> 16);
}
__device__ __forceinline__ float bf2f(short s){
    return __uint_as_float(((unsigned)(unsigned short)s) << 16);
}
__device__ __forceinline__ void split4(float4 v, bf4& h, bf4& l){
    h.x = f2bf(v.x); l.x = f2bf(v.x - bf2f(h.x));
    h.y = f2bf(v.y); l.y = f2bf(v.y - bf2f(h.y));
    h.z = f2bf(v.z); l.z = f2bf(v.z - bf2f(h.z));
    h.w = f2bf(v.w); l.w = f2bf(v.w - bf2f(h.w));
}
__device__ __forceinline__ f4 mfma_(bf8 a, bf8 b, f4 c){
    return __builtin_amdgcn_mfma_f32_16x16x32_bf16(a, b, c, 0, 0, 0);
}

enum { A_PLAIN=0, A_ADD=1, A_RELUB=2, A_EDGE=3, A_CAT3=4, A_CAT2R=5 };
enum { E_STORE=0, E_RELU=1, E_BIAS=2, E_BIASRELU=3 };

// ---------- MFMA split-bf16 GEMM: C[M,N] = epi(A[M,K] @ W[N,K]^T), ~f32 accuracy ----------
template<int AM, int EM>
__global__ __launch_bounds__(256, 2)
void mgemm(const float* __restrict__ A0, const float* __restrict__ A1,
           const float* __restrict__ A2, const float* __restrict__ W,
           const float* __restrict__ bias, float* __restrict__ C,
           int M, int N, int K, int lda,
           const int* __restrict__ i0, const int* __restrict__ i1,
           const int* __restrict__ i2)
{
    __shared__ short Ah[128][40], Al[128][40], Bh[128][40], Bl[128][40];
    const int t  = threadIdx.x;
    const int kc = t & 7, lr = t >> 3;
    const int lane = t & 63, wv = t >> 6;
    const int wm = wv >> 1, wn = wv & 1;
    const int frow = lane & 15, fk = (lane >> 4) * 8;
    const int row0 = blockIdx.y * 128, col0 = blockIdx.x * 128;

    f4 acc[4][4] = {};

    for (int k0 = 0; k0 < K; k0 += 32) {
        const int gk = k0 + kc * 4;
        const int kk = kc * 4;
        #pragma unroll
        for (int ri = 0; ri < 4; ri++) {
            int row = lr + 32 * ri;
            int grow = row0 + row;
            float4 v;
            if (AM == A_PLAIN) {
                v = ld4(A0 + (size_t)grow * lda + gk);
            } else if (AM == A_ADD) {
                v = add4(ld4(A0 + (size_t)grow * lda + gk),
                         ld4(A1 + (size_t)grow * lda + gk));
            } else if (AM == A_RELUB) {
                v = relu4(add4(ld4(A0 + (size_t)grow * lda + gk), ld4(A1 + gk)));
            } else if (AM == A_EDGE) {
                if (gk < NEMB)            v = ld4(A0 + (size_t)i0[grow] * NEMB + gk);
                else if (gk < NEMB+REMB)  v = ld4(A1 + (size_t)i1[grow] * REMB + (gk - NEMB));
                else                      v = ld4(A0 + (size_t)i2[grow] * NEMB + (gk - NEMB - REMB));
            } else if (AM == A_CAT3) {
                if (gk < HD)        v = ld4(A0 + (size_t)grow * HD + gk);
                else if (gk < 2*HD) v = ld4(A1 + (size_t)grow * HD + gk - HD);
                else                v = ld4(A2 + (size_t)grow * HD + gk - 2*HD);
            } else { // A_CAT2R
                v = (gk < HD) ? relu4(ld4(A0 + (size_t)grow * HD + gk))
                              : relu4(ld4(A1 + (size_t)grow * HD + gk - HD));
            }
            bf4 h, l; split4(v, h, l);
            *(bf4*)&Ah[row][kk] = h;
            *(bf4*)&Al[row][kk] = l;
        }
        #pragma unroll
        for (int ri = 0; ri < 4; ri++) {
            int wr = lr + 32 * ri;
            float4 v = ld4(W + (size_t)(col0 + wr) * K + gk);
            bf4 h, l; split4(v, h, l);
            *(bf4*)&Bh[wr][kk] = h;
            *(bf4*)&Bl[wr][kk] = l;
        }
        __syncthreads();
        bf8 ah[4], al[4], bh[4], bl[4];
        #pragma unroll
        for (int mi = 0; mi < 4; mi++) {
            ah[mi] = *(const bf8*)&Ah[wm*64 + mi*16 + frow][fk];
            al[mi] = *(const bf8*)&Al[wm*64 + mi*16 + frow][fk];
        }
        #pragma unroll
        for (int ni = 0; ni < 4; ni++) {
            bh[ni] = *(const bf8*)&Bh[wn*64 + ni*16 + frow][fk];
            bl[ni] = *(const bf8*)&Bl[wn*64 + ni*16 + frow][fk];
        }
        #pragma unroll
        for (int mi = 0; mi < 4; mi++)
            #pragma unroll
            for (int ni = 0; ni < 4; ni++) {
                acc[mi][ni] = mfma_(ah[mi], bh[ni], acc[mi][ni]);
                acc[mi][ni] = mfma_(ah[mi], bl[ni], acc[mi][ni]);
                acc[mi][ni] = mfma_(al[mi], bh[ni], acc[mi][ni]);
            }
        __syncthreads();
    }
    #pragma unroll
    for (int mi = 0; mi < 4; mi++) {
        #pragma unroll
        for (int ni = 0; ni < 4; ni++) {
            int ccol = col0 + wn*64 + ni*16 + frow;
            int rbase = row0 + wm*64 + mi*16 + (lane >> 4) * 4;
            #pragma unroll
            for (int reg = 0; reg < 4; reg++) {
                float v = acc[mi][ni][reg];
                if (EM == E_BIAS || EM == E_BIASRELU) v += bias[ccol];
                if (EM == E_RELU || EM == E_BIASRELU) v = relu_(v);
                C[(size_t)(rbase + reg) * N + ccol] = v;
            }
        }
    }
}

// ---------- MFMA attention: s[e] = sigmoid( tanh(me@W1L^T + term[g]) . W2 ) ----------
template<int MODE>
__global__ __launch_bounds__(256, 2)
void mattn(const float* __restrict__ ie, const float* __restrict__ tmp,
           const int* __restrict__ src,
           const float* __restrict__ W1, const float* __restrict__ W2,
           const float* __restrict__ term, float* __restrict__ sbuf)
{
    __shared__ short Ah[64][40], Al[64][40], Bh[256][40], Bl[256][40];
    __shared__ float part[4][64];
    const int t = threadIdx.x;
    const int kc = t & 7, lr = t >> 3;
    const int lane = t & 63, wv = t >> 6;        // wave owns n-range wv*64
    const int frow = lane & 15, fk = (lane >> 4) * 8;
    const int r0 = blockIdx.x * 64;

    f4 acc[4][4] = {};

    for (int k0 = 0; k0 < HD; k0 += 32) {
        const int gk = k0 + kc * 4;
        const int kk = kc * 4;
        #pragma unroll
        for (int ri = 0; ri < 2; ri++) {
            int row = lr + 32 * ri;
            int e = r0 + row;
            float4 v = ld4(ie + (size_t)e * HD + gk);
            if (MODE) v = relu4(add4(v, ld4(tmp + (size_t)src[e] * HD + gk)));
            bf4 h, l; split4(v, h, l);
            *(bf4*)&Ah[row][kk] = h;
            *(bf4*)&Al[row][kk] = l;
        }
        #pragma unroll
        for (int ri = 0; ri < 8; ri++) {
            int wr = lr + 32 * ri;
            float4 v = ld4(W1 + (size_t)wr * 512 + gk);   // left half of [256,512]
            bf4 h, l; split4(v, h, l);
            *(bf4*)&Bh[wr][kk] = h;
            *(bf4*)&Bl[wr][kk] = l;
        }
        __syncthreads();
        bf8 ah[4], al[4], bh[4], bl[4];
        #pragma unroll
        for (int mi = 0; mi < 4; mi++) {
            ah[mi] = *(const bf8*)&Ah[mi*16 + frow][fk];
            al[mi] = *(const bf8*)&Al[mi*16 + frow][fk];
        }
        #pragma unroll
        for (int ni = 0; ni < 4; ni++) {
            bh[ni] = *(const bf8*)&Bh[wv*64 + ni*16 + frow][fk];
            bl[ni] = *(const bf8*)&Bl[wv*64 + ni*16 + frow][fk];
        }
        #pragma unroll
        for (int mi = 0; mi < 4; mi++)
            #pragma unroll
            for (int ni = 0; ni < 4; ni++) {
                acc[mi][ni] = mfma_(ah[mi], bh[ni], acc[mi][ni]);
                acc[mi][ni] = mfma_(ah[mi], bl[ni], acc[mi][ni]);
                acc[mi][ni] = mfma_(al[mi], bh[ni], acc[mi][ni]);
            }
        __syncthreads();
    }
    // epilogue: per row, sum tanh(acc + term)*W2 over all 256 cols
    #pragma unroll
    for (int mi = 0; mi < 4; mi++) {
        #pragma unroll
        for (int reg = 0; reg < 4; reg++) {
            int rl = mi*16 + (lane >> 4) * 4 + reg;
            int g = (r0 + rl) / Eg;
            float p = 0.f;
            #pragma unroll
            for (int ni = 0; ni < 4; ni++) {
                int n = wv*64 + ni*16 + frow;
                p += tanhf(acc[mi][ni][reg] + term[g*HD + n]) * W2[n];
            }
            p += __shfl_xor(p, 1); p += __shfl_xor(p, 2);
            p += __shfl_xor(p, 4); p += __shfl_xor(p, 8);
            if (frow == 0) part[wv][rl] = p;
        }
    }
    __syncthreads();
    if (t < 64) {
        float p = part[0][t] + part[1][t] + part[2][t] + part[3][t];
        sbuf[r0 + t] = sigm_(p);
    }
}

// ------- CSR-gather aggregation: agg[n] = sum_{e: dst[e]==n} me(e) * s[e] -------
template<int MODE>
__global__ __launch_bounds__(256)
void agg_gather(const float* __restrict__ ie, const float* __restrict__ tmp,
                const int* __restrict__ src, const int* __restrict__ rowptr,
                const int* __restrict__ eidx, const float* __restrict__ s,
                float* __restrict__ agg)
{
    int node = blockIdx.x * 4 + (threadIdx.x >> 6);
    int c = (threadIdx.x & 63) * 4;
    float4 acc{0.f, 0.f, 0.f, 0.f};
    int beg = rowptr[node], end = rowptr[node + 1];
    for (int i = beg; i < end; i++) {
        int e = eidx[i];
        float4 v = ld4(ie + (size_t)e * HD + c);
        if (MODE) v = relu4(add4(v, ld4(tmp + (size_t)src[e] * HD + c)));
        float sc = s[e];
        acc.x += v.x * sc; acc.y += v.y * sc;
        acc.z += v.z * sc; acc.w += v.w * sc;
    }
    st4(agg + (size_t)node * HD + c, acc);
}

// ------------- CSR build -------------
__global__ void zeroi_kernel(int* __restrict__ p)
{
    p[blockIdx.x * 256 + threadIdx.x] = 0;
}
__global__ void csr_count(const int* __restrict__ dst, int* __restrict__ cnt)
{
    int e = blockIdx.x * 256 + threadIdx.x;
    atomicAdd(&cnt[dst[e]], 1);
}
__global__ void csr_scan(const int* __restrict__ cnt, int* __restrict__ rowptr)
{
    __shared__ int ws[4];
    __shared__ int carry;
    int tid = threadIdx.x;
    if (tid == 0) carry = 0;
    __syncthreads();
    for (int i = 0; i < TNODE; i += 256) {
        int v = cnt[i + tid];
        int x = v;
        #pragma unroll
        for (int off = 1; off < 64; off <<= 1) {
            int y = __shfl_up(x, off);
            if ((tid & 63) >= off) x += y;
        }
        if ((tid & 63) == 63) ws[tid >> 6] = x;
        __syncthreads();
        int add = carry;
        int w = tid >> 6;
        for (int j = 0; j < w; j++) add += ws[j];
        rowptr[i + tid] = add + x - v;      // exclusive
        __syncthreads();
        if (tid == 255) carry = add + x;
        __syncthreads();
    }
    if (tid == 0) rowptr[TNODE] = carry;
}
__global__ void csr_fill(const int* __restrict__ dst, const int* __restrict__ rowptr,
                         int* __restrict__ fillc, int* __restrict__ eidx)
{
    int e = blockIdx.x * 256 + threadIdx.x;
    int d = dst[e];
    int slot = rowptr[d] + atomicAdd(&fillc[d], 1);
    eidx[slot] = e;
}

// ------------- per-graph attention bias terms -------------
__global__ __launch_bounds__(256)
void term_kernel(const float* __restrict__ mn, const float* __restrict__ tgt_rel,
                 const float* __restrict__ Wa1, const float* __restrict__ Wd1,
                 const int* __restrict__ srcn, const int* __restrict__ tgtn,
                 float* __restrict__ term)
{
    __shared__ float Gs[HD];
    int b = blockIdx.x % Bg;
    int which = blockIdx.x / Bg;
    int c = threadIdx.x;
    float g;
    if (which == 0)
        g = mn[(size_t)srcn[b]*HD + c] + tgt_rel[b*HD + c] - mn[(size_t)tgtn[b]*HD + c];
    else
        g = tgt_rel[b*HD + c];
    Gs[c] = g;
    __syncthreads();
    const float* W = (which == 0) ? Wa1 : (Wd1 + (size_t)(which-1)*HD*512);
    float p = 0.f;
    for (int k = 0; k < HD; k += 4) {
        float4 w = ld4(W + (size_t)c*512 + 256 + k);
        p = fmaf(Gs[k], w.x, p); p = fmaf(Gs[k+1], w.y, p);
        p = fmaf(Gs[k+2], w.z, p); p = fmaf(Gs[k+3], w.w, p);
    }
    term[(size_t)which*Bg*HD + b*HD + c] = p;
}

__global__ void tgtrel_kernel(const float* __restrict__ rel_emb, const int* __restrict__ batch_rel,
                              float* __restrict__ tgt_rel)
{
    int b = blockIdx.x, c = threadIdx.x;
    tgt_rel[b*HD + c] = rel_emb[(size_t)batch_rel[b]*REMB + c];
}

__global__ void h0_kernel(const float* __restrict__ agg2, float* __restrict__ h0)
{
    int b = blockIdx.x, c = threadIdx.x;
    float m = -1e30f;
    for (int n = 0; n < Nn; n++)
        m = fmaxf(m, agg2[((size_t)b*Nn + n)*HD + c]);
    h0[b*HD + c] = m;
}

// ------------- transpose w_hh to k-major: whT[d][k][768] -------------
__global__ void whT_kernel(const float* __restrict__ whf, const float* __restrict__ whb,
                           float* __restrict__ whT)
{
    int d = blockIdx.x >> 8, k = blockIdx.x & 255;
    const float* w = d ? whb : whf;
    int c = threadIdx.x;
    whT[((size_t)d*256 + k)*768 + c] = w[(size_t)c*256 + k];
}

// ------------- whole GRU: 128 blocks x 1024 thr, 2 seqs/block, 4-way k-split -------------
__global__ __launch_bounds__(1024)
void gru_all(const float* __restrict__ gi_f, const float* __restrict__ gi_b,
             const float* __restrict__ whT,
             const float* __restrict__ bhf, const float* __restrict__ bhb,
             const float* __restrict__ h0,
             float* __restrict__ outf, float* __restrict__ outb)
{
    __shared__ float hs[2][256];
    __shared__ float part[4][6][256];   // [kc][seq*3+gate][h]
    int blk = blockIdx.x;
    int d = blk >> 6, r0 = (blk & 63) * 2;
    int tid = threadIdx.x;
    int kc = tid >> 8, h = tid & 255;

    if (kc < 2) hs[kc][h] = h0[(size_t)(r0 + kc) * HD + h];

    const float* wt  = whT + (size_t)d * 256 * 768;
    const float* gi  = d ? gi_b : gi_f;
    const float* bh  = d ? bhb : bhf;
    float* outp      = d ? outb : outf;
    const float bhr = bh[h], bhz = bh[256 + h], bhn = bh[512 + h];
    const int kbase = kc * 64;
    __syncthreads();

    for (int t = 0; t < Nn; t++) {
        float ar0=0.f, az0=0.f, an0=0.f, ar1=0.f, az1=0.f, an1=0.f;
        #pragma unroll 8
        for (int k2 = 0; k2 < 64; k2++) {
            int k = kbase + k2;
            const float* wk = wt + (size_t)k * 768;
            float wr = wk[h], wz = wk[256 + h], wn = wk[512 + h];
            float hv0 = hs[0][k], hv1 = hs[1][k];
            ar0 = fmaf(hv0, wr, ar0); az0 = fmaf(hv0, wz, az0); an0 = fmaf(hv0, wn, an0);
            ar1 = fmaf(hv1, wr, ar1); az1 = fmaf(hv1, wz, az1); an1 = fmaf(hv1, wn, an1);
        }
        part[kc][0][h] = ar0; part[kc][1][h] = az0; part[kc][2][h] = an0;
        part[kc][3][h] = ar1; part[kc][4][h] = az1; part[kc][5][h] = an1;
        __syncthreads();
        float nh = 0.f;
        if (kc < 2) {
            int seq = kc;
            int trow = d ? (Nn - 1 - t) : t;
            float R = 0.f, Z = 0.f, NN = 0.f;
            #pragma unroll
            for (int q = 0; q < 4; q++) {
                R  += part[q][seq*3 + 0][h];
                Z  += part[q][seq*3 + 1][h];
                NN += part[q][seq*3 + 2][h];
            }
            size_t girow = ((size_t)(r0 + seq) * Nn + trow) * 768;
            float hprev = hs[seq][h];
            float r = sigm_(gi[girow + h]       + R + bhr);
            float z = sigm_(gi[girow + 256 + h] + Z + bhz);
            float n = tanhf(gi[girow + 512 + h] + r * (NN + bhn));
            nh = (1.f - z) * n + z * hprev;
            outp[((size_t)(r0 + seq) * Nn + trow) * HD + h] = nh;
        }
        __syncthreads();
        if (kc < 2) hs[kc][h] = nh;
        __syncthreads();
    }
}

__global__ __launch_bounds__(256)
void final_kernel(const float* __restrict__ atom_h, const float* __restrict__ tgt_rel,
                  const int* __restrict__ srcn, const int* __restrict__ tgtn,
                  const float* __restrict__ Wl, const float* __restrict__ bl,
                  float* __restrict__ out)
{
    __shared__ float red[4];
    int b = blockIdx.x, c = threadIdx.x;
    float v = tanhf(atom_h[(size_t)srcn[b]*HD + c] + tgt_rel[b*HD + c]
                    - atom_h[(size_t)tgtn[b]*HD + c]);
    float p = v * Wl[c];
    #pragma unroll
    for (int off = 1; off < 64; off <<= 1) p += __shfl_xor(p, off);
    int wv = c >> 6;
    if ((c & 63) == 0) red[wv] = p;
    __syncthreads();
    if (c == 0) out[b] = red[0] + red[1] + red[2] + red[3] + bl[0];
}

extern "C" void kernel_launch(void* const* d_in, const int* in_sizes, int n_in,
                              void* d_out, int out_size, void* d_ws, size_t ws_size,
                              hipStream_t stream)
{
    const float* node_feat = (const float*)d_in[0];
    const float* rel_emb   = (const float*)d_in[1];
    const float* W_i_node  = (const float*)d_in[2];
    const float* W_i_edge  = (const float*)d_in[3];
    const float* Wa1       = (const float*)d_in[4];
    const float* Wa2       = (const float*)d_in[5];
    const float* W_h_atom  = (const float*)d_in[6];
    const float* W_h_bond  = (const float*)d_in[7];
    const float* Wd1       = (const float*)d_in[8];
    const float* Wd2       = (const float*)d_in[9];
    const float* W_comm    = (const float*)d_in[10];
    const float* gru_bias  = (const float*)d_in[11];
    const float* w_ih_f    = (const float*)d_in[12];
    const float* w_hh_f    = (const float*)d_in[13];
    const float* b_ih_f    = (const float*)d_in[14];
    const float* b_hh_f    = (const float*)d_in[15];
    const float* w_ih_b    = (const float*)d_in[16];
    const float* w_hh_b    = (const float*)d_in[17];
    const float* b_ih_b    = (const float*)d_in[18];
    const float* b_hh_b    = (const float*)d_in[19];
    const float* W_o       = (const float*)d_in[20];
    const float* b_o       = (const float*)d_in[21];
    const float* W_lin1    = (const float*)d_in[22];
    const float* b_lin1    = (const float*)d_in[23];
    const int* edge_src  = (const int*)d_in[24];
    const int* edge_dst  = (const int*)d_in[25];
    const int* edge_rel  = (const int*)d_in[26];
    const int* batch_rel = (const int*)d_in[27];
    const int* src_node  = (const int*)d_in[28];
    const int* tgt_node  = (const int*)d_in[29];
    float* out = (float*)d_out;

    float* ws = (float*)d_ws;
    size_t off = 0;
    auto alloc = [&](size_t n){ float* p = ws + off; off += n; return p; };
    float* tgt_rel    = alloc((size_t)Bg*HD);
    float* term       = alloc((size_t)3*Bg*HD);
    float* input_node = alloc((size_t)TNODE*HD);
    float* mn_a       = alloc((size_t)TNODE*HD);
    float* mn_b       = alloc((size_t)TNODE*HD);
    float* agg        = alloc((size_t)TNODE*HD);
    float* h0v        = alloc((size_t)Bg*HD);
    float* whT        = alloc((size_t)2*256*768);
    float* sbuf       = alloc((size_t)TEDGE);
    int*   cnt        = (int*)alloc((size_t)TNODE);
    int*   fillc      = (int*)alloc((size_t)TNODE);
    int*   rowptr     = (int*)alloc((size_t)TNODE + 256);
    int*   eidx       = (int*)alloc((size_t)TEDGE);
    float* input_edge = alloc((size_t)TEDGE*HD);
    // aliases (lifetimes disjoint):
    float* agg2  = mn_a;                              // after last attn/gather
    float* gi_f  = input_edge;                        // after last attn/gather
    float* gi_b  = input_edge + (size_t)TNODE*768;
    float* out_f = input_edge + (size_t)2*TNODE*768;
    float* out_b = out_f + (size_t)TNODE*HD;
    float* atom_h = input_node;                       // after W_comm GEMM

    tgtrel_kernel<<<Bg, 256, 0, stream>>>(rel_emb, batch_rel, tgt_rel);
    whT_kernel<<<512, 768, 0, stream>>>(w_hh_f, w_hh_b, whT);

    // ---- CSR build (dst-sorted incidence) ----
    zeroi_kernel<<<2*TNODE/256, 256, 0, stream>>>(cnt);     // zeros cnt AND fillc (adjacent)
    csr_count<<<TEDGE/256, 256, 0, stream>>>(edge_dst, cnt);
    csr_scan<<<1, 256, 0, stream>>>(cnt, rowptr);
    csr_fill<<<TEDGE/256, 256, 0, stream>>>(edge_dst, rowptr, fillc, eidx);

    // input_node = relu(node_feat @ W_i_node^T)
    mgemm<A_PLAIN, E_RELU><<<dim3(HD/128, TNODE/128), 256, 0, stream>>>(
        node_feat, nullptr, nullptr, W_i_node, nullptr, input_node,
        TNODE, HD, NEMB, NEMB, nullptr, nullptr, nullptr);

    // input_edge = relu(edge_feat @ W_i_edge^T)
    mgemm<A_EDGE, E_RELU><<<dim3(HD/128, TEDGE/128), 256, 0, stream>>>(
        node_feat, rel_emb, nullptr, W_i_edge, nullptr, input_edge,
        TEDGE, HD, 512, 0, edge_src, edge_rel, edge_dst);

    term_kernel<<<3*Bg, 256, 0, stream>>>(input_node, tgt_rel, Wa1, Wd1,
                                          src_node, tgt_node, term);

    // ---- input attention scale + gather-aggregate ----
    mattn<0><<<TEDGE/64, 256, 0, stream>>>(input_edge, nullptr, edge_src,
                                           Wa1, Wa2, term, sbuf);
    agg_gather<0><<<TNODE/4, 256, 0, stream>>>(input_edge, nullptr, edge_src,
                                               rowptr, eidx, sbuf, agg);

    const float* mn_cur = input_node;
    float* bufs[2] = {mn_a, mn_b};
    for (int d = 0; d < 2; d++) {
        float* mn_next = bufs[d];
        float* tmp     = bufs[1-d];
        mgemm<A_ADD, E_RELU><<<dim3(2, TNODE/128), 256, 0, stream>>>(
            mn_cur, agg, nullptr, W_h_atom + (size_t)d*HD*HD, nullptr, mn_next,
            TNODE, HD, HD, HD, nullptr, nullptr, nullptr);
        mgemm<A_PLAIN, E_STORE><<<dim3(2, TNODE/128), 256, 0, stream>>>(
            mn_next, nullptr, nullptr, W_h_bond + (size_t)d*HD*HD, nullptr, tmp,
            TNODE, HD, HD, HD, nullptr, nullptr, nullptr);
        mattn<1><<<TEDGE/64, 256, 0, stream>>>(input_edge, tmp, edge_src,
            Wd1 + (size_t)d*HD*512, Wd2 + (size_t)d*HD, term + (size_t)(1+d)*Bg*HD, sbuf);
        agg_gather<1><<<TNODE/4, 256, 0, stream>>>(input_edge, tmp, edge_src,
            rowptr, eidx, sbuf, agg);
        mn_cur = mn_next;
    }

    // agg2 = concat([agg, mn, input_node]) @ W_comm^T   (agg2 aliases mn_a)
    mgemm<A_CAT3, E_STORE><<<dim3(2, TNODE/128), 256, 0, stream>>>(
        agg, (const float*)mn_cur, input_node, W_comm, nullptr, agg2,
        TNODE, HD, 3*HD, 0, nullptr, nullptr, nullptr);

    h0_kernel<<<Bg, 256, 0, stream>>>(agg2, h0v);

    // gi = relu(agg2 + gru_bias) @ w_ih^T + b_ih   (both directions)
    mgemm<A_RELUB, E_BIAS><<<dim3(768/128, TNODE/128), 256, 0, stream>>>(
        agg2, gru_bias, nullptr, w_ih_f, b_ih_f, gi_f,
        TNODE, 768, HD, HD, nullptr, nullptr, nullptr);
    mgemm<A_RELUB, E_BIAS><<<dim3(768/128, TNODE/128), 256, 0, stream>>>(
        agg2, gru_bias, nullptr, w_ih_b, b_ih_b, gi_b,
        TNODE, 768, HD, HD, nullptr, nullptr, nullptr);

    gru_all<<<128, 1024, 0, stream>>>(gi_f, gi_b, whT, b_hh_f, b_hh_b, h0v,
                                      out_f, out_b);

    // atom_h = relu(relu(concat(out_f,out_b)) @ W_o^T + b_o)
    mgemm<A_CAT2R, E_BIASRELU><<<dim3(2, TNODE/128), 256, 0, stream>>>(
        out_f, out_b, nullptr, W_o, b_o, atom_h,
        TNODE, HD, 2*HD, 0, nullptr, nullptr, nullptr);

    final_kernel<<<Bg, 256, 0, stream>>>(atom_h, tgt_rel, src_node, tgt_node,
                                         W_lin1, b_lin1, out);
}